// Round 1
// baseline (799.072 us; speedup 1.0000x reference)
//
#include <hip/hip_runtime.h>

#define TIMESTEPS 1000
#define NB 512
#define TP 256
#define TFF 64
#define DFF 64
#define DSS 32
#define DMM 512
#define HID 512
#define NE 6

// ws float offsets
#define WS_ALPHAS   0        // 1000
#define WS_FREQS    1024     // 256
#define WS_PROBS    1536     // 512*6
#define WS_SELECTED 4608     // 512 ints
#define WS_LOSSB    5632     // 512
#define WS_GCTX     8192     // 512*512
#define WS_OUTSUB   270336   // 6*4*64*64

__device__ __forceinline__ float gelu_f(float x){
    float x3 = x*x*x;
    return 0.5f*x*(1.0f + tanhf(0.7978845608028654f*(x + 0.044715f*x3)));
}

__global__ void k0_init(float* __restrict__ ws){
    int tid = threadIdx.x;
    for(int k = tid; k < 256; k += blockDim.x)
        ws[WS_FREQS + k] = expf(-logf(10000.0f) * (float)k / 256.0f);
    if(tid == 0){
        float prod = 1.0f;
        const float b0 = 0.0001f, b1v = 0.02f;
        for(int i = 0; i < TIMESTEPS; i++){
            float beta = b0 + (b1v - b0) * ((float)i / (float)(TIMESTEPS - 1));
            prod *= (1.0f - beta);
            ws[WS_ALPHAS + i] = prod;
        }
    }
}

// one block per batch sample; global_ctx[b, :] = mean_tp gelu(obs@Wenc + stat@Wstat + benc)
__global__ __launch_bounds__(512) void k1_encoder(
    const float* __restrict__ obs, const float* __restrict__ stat,
    const float* __restrict__ Wenc, const float* __restrict__ benc,
    const float* __restrict__ Wstat, float* __restrict__ ws){
    __shared__ float sW[64*512];   // 128 KB
    __shared__ float sObs[8*64];
    __shared__ float sStat[32];
    int b = blockIdx.x, tid = threadIdx.x;
    for(int i = tid; i < 64*512; i += 512) sW[i] = Wenc[i];
    if(tid < 32) sStat[tid] = stat[b*DSS + tid];
    __syncthreads();
    int j = tid;
    float statj = benc[j];
    for(int s = 0; s < 32; s++) statj += sStat[s] * Wstat[s*512 + j];
    float acc = 0.f;
    for(int c = 0; c < 32; c++){
        __syncthreads();
        sObs[tid] = obs[(b*TP + c*8)*64 + tid];   // 8 rows x 64
        __syncthreads();
        #pragma unroll 2
        for(int r = 0; r < 8; r++){
            const float* orow = &sObs[r*64];
            float v = statj;
            #pragma unroll
            for(int f = 0; f < 64; f++) v += orow[f] * sW[f*512 + j];
            acc += gelu_f(v);
        }
    }
    ws[WS_GCTX + b*512 + j] = acc * (1.0f/256.0f);
}

// one wave per sample: router logits -> softmax probs + selected
__global__ __launch_bounds__(64) void k2_router(
    const float* __restrict__ Wr, const float* __restrict__ br,
    const int* __restrict__ phase, float* __restrict__ ws){
    int b = blockIdx.x, lane = threadIdx.x;
    const float* g = &ws[WS_GCTX + b*512];
    float acc[6] = {0,0,0,0,0,0};
    for(int k = 0; k < 8; k++){
        int d = k*64 + lane;
        float gv = g[d];
        #pragma unroll
        for(int e = 0; e < 6; e++) acc[e] += gv * Wr[d*6 + e];
    }
    #pragma unroll
    for(int off = 32; off > 0; off >>= 1)
        #pragma unroll
        for(int e = 0; e < 6; e++) acc[e] += __shfl_down(acc[e], off);
    if(lane == 0){
        float logit[6], mx = -1e30f;
        for(int e = 0; e < 6; e++){ logit[e] = acc[e] + br[e]; mx = fmaxf(mx, logit[e]); }
        float s = 0.f, p[6];
        for(int e = 0; e < 6; e++){ p[e] = expf(logit[e] - mx); s += p[e]; }
        for(int e = 0; e < 6; e++) ws[WS_PROBS + b*6 + e] = p[e] / s;
        int ph = phase[b];
        int sel = ph + ((logit[ph+3] > logit[ph]) ? 3 : 0);
        ((int*)ws)[WS_SELECTED + b] = sel;
    }
}

// per-sample expert FFN. STORE=false: selected expert, accumulate weighted loss_raw.
// STORE=true: grid 24 = (e, b<4), write outputs_all tile to ws.
template<bool STORE>
__global__ __launch_bounds__(512) void k_moe(
    const float* __restrict__ fut, const float* __restrict__ eps,
    const int* __restrict__ t_arr,
    const float* __restrict__ W1, const float* __restrict__ b1,
    const float* __restrict__ W2, const float* __restrict__ b2,
    float* __restrict__ ws){
    __shared__ float sC[1024];
    __shared__ float sHs[512];
    __shared__ float sN[8][64];
    __shared__ float sH[8][512];
    __shared__ float sRed[8];
    int tid = threadIdx.x;
    int b, e;
    if(STORE){ e = blockIdx.x / 4; b = blockIdx.x % 4; }
    else { b = blockIdx.x; e = ((const int*)ws)[WS_SELECTED + b]; }
    int tv = t_arr[b];
    float ab = ws[WS_ALPHAS + tv];
    float sa = sqrtf(ab), sb = sqrtf(1.0f - ab);
    // c_static = [global_ctx (512) | t_emb (512)]
    sC[tid] = ws[WS_GCTX + b*512 + tid];
    {
        float fr = ws[WS_FREQS + (tid & 255)];
        float arg = (float)tv * fr;
        sC[512 + tid] = (tid < 256) ? sinf(arg) : cosf(arg);
    }
    __syncthreads();
    // hstat[j] = b1 + c_static @ W1[e, 64:, j]
    {
        int j = tid;
        float acc = b1[e*512 + j];
        const float* w = &W1[(size_t)(e*1088 + 64)*512 + j];
        for(int d = 0; d < 1024; d++) acc += sC[d] * w[(size_t)d*512];
        sHs[j] = acc;
    }
    __syncthreads();
    float lsum = 0.f;
    for(int c = 0; c < 8; c++){
        {   // stage noisy: 8 tf x 64
            int idx = (b*TFF + c*8)*64 + tid;
            ((float*)sN)[tid] = sa*fut[idx] + sb*eps[idx];
        }
        __syncthreads();
        {   // h[tt][j] = gelu(hstat + noisy @ W1[e,:64,:])
            int j = tid;
            const float* w = &W1[(size_t)(e*1088)*512 + j];
            float a[8];
            #pragma unroll
            for(int tt = 0; tt < 8; tt++) a[tt] = sHs[j];
            for(int d = 0; d < 64; d++){
                float wv = w[(size_t)d*512];
                #pragma unroll
                for(int tt = 0; tt < 8; tt++) a[tt] += sN[tt][d]*wv;
            }
            #pragma unroll
            for(int tt = 0; tt < 8; tt++) sH[tt][j] = gelu_f(a[tt]);
        }
        __syncthreads();
        {   // out[tt][f] = h @ W2 + b2
            int tt = tid >> 6, f = tid & 63;
            int tf = c*8 + tt;
            float acc = b2[e*64 + f];
            const float* w2 = &W2[(size_t)e*512*64 + f];
            const float* hh = sH[tt];
            for(int j = 0; j < 512; j++) acc += hh[j]*w2[(size_t)j*64];
            if(STORE){
                ws[WS_OUTSUB + ((e*4 + b)*64 + tf)*64 + f] = acc;
            } else {
                float d = acc - eps[(b*TFF + tf)*64 + f];
                lsum += d*d;
            }
        }
        __syncthreads();
    }
    if(!STORE){
        #pragma unroll
        for(int off = 32; off > 0; off >>= 1) lsum += __shfl_down(lsum, off);
        int wid = tid >> 6;
        if((tid & 63) == 0) sRed[wid] = lsum;
        __syncthreads();
        if(tid == 0){
            float s = 0.f;
            for(int w = 0; w < 8; w++) s += sRed[w];
            const float pw[3] = {1.f, 5.f, 5.f};
            ws[WS_LOSSB + b] = (s * (1.0f/4096.0f)) * pw[e % 3];
        }
    }
}

__global__ __launch_bounds__(512) void k5_final(
    float* __restrict__ ws, float* __restrict__ out){
    __shared__ float red[512];
    int tid = threadIdx.x;
    float v = ws[WS_LOSSB + tid] * (1.0f/512.0f);  // weighted loss mean
    // chain: 7 pairs, mean over 4*64*64 each
    const int pa[7] = {0,1,3,4,0,1,2};
    const int pb[7] = {1,2,4,5,3,4,5};
    float chain = 0.f;
    for(int p = 0; p < 7; p++){
        const float* A = &ws[WS_OUTSUB + pa[p]*16384];
        const float* Bp = &ws[WS_OUTSUB + pb[p]*16384];
        float s = 0.f;
        for(int i = tid; i < 16384; i += 512){ float d = A[i] - Bp[i]; s += d*d; }
        chain += s * (1.0f/16384.0f);
    }
    // smooth: diff along tf axis; mean over (4,63,64) per expert, summed
    float sm = 0.f;
    for(int e = 0; e < 6; e++){
        const float* O = &ws[WS_OUTSUB + e*16384];
        float s = 0.f;
        for(int i = tid; i < 4*63*64; i += 512){
            int sidx = i / (63*64); int r = i % (63*64);
            int tf = r / 64; int f = r % 64;
            float d = O[(sidx*64 + tf + 1)*64 + f] - O[(sidx*64 + tf)*64 + f];
            s += d*d;
        }
        sm += s * (1.0f/16128.0f);
    }
    v += 0.01f * (chain + 0.5f * sm);
    red[tid] = v;
    __syncthreads();
    for(int s = 256; s > 0; s >>= 1){
        if(tid < s) red[tid] += red[tid + s];
        __syncthreads();
    }
    if(tid == 0){
        float total = red[0];
        float lb = 0.f;
        for(int e = 0; e < 6; e++){
            float cnt = 0.f, ps = 0.f;
            for(int bb = 0; bb < 512; bb++){
                if(((const int*)ws)[WS_SELECTED + bb] == e) cnt += 1.f;
                ps += ws[WS_PROBS + bb*6 + e];
            }
            lb += (cnt * (1.0f/512.f)) * (ps * (1.0f/512.f));
        }
        total += 0.01f * 6.0f * lb;
        out[0] = total;
    }
}

extern "C" void kernel_launch(void* const* d_in, const int* in_sizes, int n_in,
                              void* d_out, int out_size, void* d_ws, size_t ws_size,
                              hipStream_t stream){
    const float* obs  = (const float*)d_in[0];
    const float* fut  = (const float*)d_in[1];
    const float* stat = (const float*)d_in[2];
    const float* eps  = (const float*)d_in[3];
    const int*   phase= (const int*)d_in[4];
    const int*   t    = (const int*)d_in[5];
    const float* Wenc = (const float*)d_in[6];
    const float* benc = (const float*)d_in[7];
    const float* Wstat= (const float*)d_in[8];
    const float* Wr   = (const float*)d_in[9];
    const float* br   = (const float*)d_in[10];
    const float* W1   = (const float*)d_in[11];
    const float* b1   = (const float*)d_in[12];
    const float* W2   = (const float*)d_in[13];
    const float* b2   = (const float*)d_in[14];
    float* ws  = (float*)d_ws;
    float* out = (float*)d_out;

    k0_init<<<1, 256, 0, stream>>>(ws);
    k1_encoder<<<NB, 512, 0, stream>>>(obs, stat, Wenc, benc, Wstat, ws);
    k2_router<<<NB, 64, 0, stream>>>(Wr, br, phase, ws);
    k_moe<false><<<NB, 512, 0, stream>>>(fut, eps, t, W1, b1, W2, b2, ws);
    k_moe<true><<<24, 512, 0, stream>>>(fut, eps, t, W1, b1, W2, b2, ws);
    k5_final<<<1, 512, 0, stream>>>(ws, out);
}

// Round 2
// 229.498 us; speedup vs baseline: 3.4818x; 3.4818x over previous
//
#include <hip/hip_runtime.h>

typedef float  f32x4 __attribute__((ext_vector_type(4)));
typedef short  s16x8 __attribute__((ext_vector_type(8)));
typedef unsigned short u16;
typedef u16    u16x4 __attribute__((ext_vector_type(4)));

#define TIMESTEPS 1000

// ---- ws float-offset map ----
#define WS_ALPHAS   0        // 1000 f
#define WS_FREQS    1024     // 256 f
#define WS_PROBS    1536     // 512*6 f
#define WS_SELECTED 4608     // 512 int
#define WS_LOSSB    5632     // 512 f
#define WS_META     6144     // int: [0]=nch, entries (e,start,len,aux) from 6148
#define WS_PERM     6400     // 512 int
#define WS_PARTS    7168     // 13 f
#define WS_GCTX     8192     // 512*512 f
#define WS_TEMB     270336   // 512*512 f
#define WS_HSTAT    532480   // 512*512 f
#define WS_HSTAT2   794624   // 6*4*512 f
#define WS_OUTSUB   806912   // 6*4*64*64 f
#define WS_U16BYTE  3620864  // byte offset of u16 region (16B aligned)
// u16-offsets inside u16 region
#define U_WENCT     0        // 512*64
#define U_W1T       32768    // 6*512*1088
#define U_W2T       3375104  // 6*64*512

__device__ __forceinline__ u16 f2bf(float x){
    unsigned u = __builtin_bit_cast(unsigned, x);
    unsigned r = (u + 0x7FFFu + ((u >> 16) & 1u)) >> 16;
    return (u16)r;
}

__device__ __forceinline__ float gelu_f(float x){
    // 0.5x(1+tanh(0.79788456(x+0.044715x^3))) == x*(1-r), r=1/(exp2(t*2/ln2)+1)
    float x2 = x * x;
    float t  = x * fmaf(0.035677408136f, x2, 0.7978845608028654f);
    float ex = exp2f(t * 2.885390081777927f);
    float r  = 1.0f / (ex + 1.0f);
    return x * (1.0f - r);
}

__device__ __forceinline__ void mfma16(f32x4& c, s16x8 a, s16x8 b){
    asm volatile("v_mfma_f32_16x16x32_bf16 %0, %1, %2, %0" : "+v"(c) : "v"(a), "v"(b));
}

// ---------------- k0: alphas_bar + freqs ----------------
__global__ void k0_init(float* __restrict__ ws){
    int tid = threadIdx.x;
    for(int k = tid; k < 256; k += blockDim.x)
        ws[WS_FREQS + k] = expf(-logf(10000.0f) * (float)k / 256.0f);
    if(tid == 0){
        float prod = 1.0f;
        const float b0 = 0.0001f, b1v = 0.02f;
        for(int i = 0; i < TIMESTEPS; i++){
            float beta = b0 + (b1v - b0) * ((float)i / (float)(TIMESTEPS - 1));
            prod *= (1.0f - beta);
            ws[WS_ALPHAS + i] = prod;
        }
    }
}

// ---------------- k0T: fp32 [K][J] -> bf16 [J][K] transposes ----------------
__global__ __launch_bounds__(256) void k0T(const float* __restrict__ Wenc,
                                           const float* __restrict__ W1,
                                           const float* __restrict__ W2,
                                           u16* __restrict__ uws){
    __shared__ float sT[32][33];
    int bid = blockIdx.x;
    const float* src; u16* dst; int K, J, kt, jt;
    const int t1 = 6*34*16, t2 = t1 + 6*16*2;
    if(bid < t1){
        int e = bid / 544, r = bid % 544; kt = r / 16; jt = r % 16;
        src = W1 + (size_t)e*1088*512; dst = uws + U_W1T + (size_t)e*512*1088; K = 1088; J = 512;
    } else if(bid < t2){
        int r = bid - t1; int e = r / 32; r %= 32; kt = r / 2; jt = r % 2;
        src = W2 + (size_t)e*512*64; dst = uws + U_W2T + (size_t)e*64*512; K = 512; J = 64;
    } else {
        int r = bid - t2; kt = r / 16; jt = r % 16;
        src = Wenc; dst = uws + U_WENCT; K = 64; J = 512;
    }
    int ty = threadIdx.x >> 5, tx = threadIdx.x & 31;
    #pragma unroll
    for(int i = 0; i < 4; i++)
        sT[ty + i*8][tx] = src[(size_t)(kt*32 + ty + i*8)*J + jt*32 + tx];
    __syncthreads();
    #pragma unroll
    for(int i = 0; i < 4; i++)
        dst[(size_t)(jt*32 + ty + i*8)*K + kt*32 + tx] = f2bf(sT[tx][ty + i*8]);
}

// ---------------- k1: encoder via MFMA ----------------
#define PADX 72
__global__ __launch_bounds__(512) void k1_enc_mfma(const float* __restrict__ obs,
        const float* __restrict__ stat, const float* __restrict__ Wstat,
        const float* __restrict__ benc, const u16* __restrict__ uws,
        float* __restrict__ ws){
    __shared__ u16  sX[256 * PADX];
    __shared__ float sBias[512];
    __shared__ float sStat[32];
    int b = blockIdx.x, tid = threadIdx.x;
    if(tid < 32) sStat[tid] = stat[b*32 + tid];
    {   // stage obs -> bf16 LDS: thread: row=tid>>1, 32 cols
        int row = tid >> 1, c0 = (tid & 1) * 32;
        const f32x4* src = (const f32x4*)&obs[((size_t)b*256 + row)*64 + c0];
        u16* dst = &sX[row*PADX + c0];
        #pragma unroll
        for(int i = 0; i < 8; i++){
            f32x4 v = src[i];
            u16x4 p; p.x = f2bf(v.x); p.y = f2bf(v.y); p.z = f2bf(v.z); p.w = f2bf(v.w);
            *(u16x4*)(dst + i*4) = p;
        }
    }
    __syncthreads();
    {   // per-column bias = benc + stat@Wstat
        float v = benc[tid];
        for(int s = 0; s < 32; s++) v += sStat[s] * Wstat[s*512 + tid];
        sBias[tid] = v;
    }
    __syncthreads();
    int w = tid >> 6, l = tid & 63, lr = l & 15, lk = (l >> 4) * 8;
    const u16* wencT = uws + U_WENCT;
    s16x8 bf[4][2];
    float bias[4];
    #pragma unroll
    for(int n = 0; n < 4; n++){
        int col = w*64 + n*16 + lr;
        bf[n][0] = *(const s16x8*)&wencT[col*64 + lk];
        bf[n][1] = *(const s16x8*)&wencT[col*64 + 32 + lk];
        bias[n]  = sBias[col];
    }
    float cac[4] = {0.f, 0.f, 0.f, 0.f};
    for(int mt = 0; mt < 16; mt++){
        s16x8 a0 = *(const s16x8*)&sX[(mt*16 + lr)*PADX + lk];
        s16x8 a1 = *(const s16x8*)&sX[(mt*16 + lr)*PADX + 32 + lk];
        #pragma unroll
        for(int n = 0; n < 4; n++){
            f32x4 acc = {bias[n], bias[n], bias[n], bias[n]};
            mfma16(acc, a0, bf[n][0]);
            mfma16(acc, a1, bf[n][1]);
            cac[n] += gelu_f(acc.x) + gelu_f(acc.y) + gelu_f(acc.z) + gelu_f(acc.w);
        }
    }
    #pragma unroll
    for(int n = 0; n < 4; n++){
        cac[n] += __shfl_xor(cac[n], 16);
        cac[n] += __shfl_xor(cac[n], 32);
    }
    if(l < 16){
        #pragma unroll
        for(int n = 0; n < 4; n++)
            ws[WS_GCTX + b*512 + w*64 + n*16 + l] = cac[n] * (1.0f/256.0f);
    }
}

// ---------------- k2: router + selection + t-embedding ----------------
__global__ __launch_bounds__(64) void k2_router(const float* __restrict__ Wr,
        const float* __restrict__ br, const int* __restrict__ phase,
        const int* __restrict__ t_arr, float* __restrict__ ws){
    int b = blockIdx.x, lane = threadIdx.x;
    const float* g = &ws[WS_GCTX + b*512];
    float acc[6] = {0,0,0,0,0,0};
    for(int k = 0; k < 8; k++){
        int d = k*64 + lane;
        float gv = g[d];
        #pragma unroll
        for(int e = 0; e < 6; e++) acc[e] += gv * Wr[d*6 + e];
    }
    #pragma unroll
    for(int off = 32; off > 0; off >>= 1)
        #pragma unroll
        for(int e = 0; e < 6; e++) acc[e] += __shfl_down(acc[e], off);
    int tv = t_arr[b];
    for(int k = 0; k < 8; k++){
        int d = k*64 + lane;
        float fr = ws[WS_FREQS + (d & 255)];
        float a = (float)tv * fr;
        ws[WS_TEMB + b*512 + d] = (d < 256) ? sinf(a) : cosf(a);
    }
    if(lane == 0){
        float logit[6], mx = -1e30f;
        #pragma unroll
        for(int e = 0; e < 6; e++){ logit[e] = acc[e] + br[e]; mx = fmaxf(mx, logit[e]); }
        float s = 0.f, p[6];
        #pragma unroll
        for(int e = 0; e < 6; e++){ p[e] = expf(logit[e] - mx); s += p[e]; }
        float inv = 1.0f / s;
        #pragma unroll
        for(int e = 0; e < 6; e++) ws[WS_PROBS + b*6 + e] = p[e] * inv;
        int ph = phase[b];
        int sel = ph + ((logit[ph + 3] > logit[ph]) ? 3 : 0);
        ((int*)ws)[WS_SELECTED + b] = sel;
    }
}

// ---------------- k2b: group samples by expert (deterministic) ----------------
__global__ __launch_bounds__(512) void k2b_group(float* __restrict__ ws){
    __shared__ int ssel[512];
    __shared__ int sCnt[6], sOff[6];
    int tid = threadIdx.x;
    int* wsi = (int*)ws;
    int sv = wsi[WS_SELECTED + tid];
    ssel[tid] = sv;
    __syncthreads();
    if(tid < 6){
        int c = 0;
        for(int i = 0; i < 512; i++) c += (ssel[i] == tid);
        sCnt[tid] = c;
    }
    int rank = 0;
    for(int i = 0; i < tid; i++) rank += (ssel[i] == sv);
    __syncthreads();
    if(tid == 0){
        int o = 0;
        for(int e = 0; e < 6; e++){ sOff[e] = o; o += sCnt[e]; }
    }
    __syncthreads();
    wsi[WS_PERM + sOff[sv] + rank] = tid;
    if(tid == 0){
        int nch = 0;
        for(int e = 0; e < 6; e++){
            for(int s = 0; s < sCnt[e]; s += 64){
                int len = sCnt[e] - s; if(len > 64) len = 64;
                wsi[WS_META + 4 + nch*4 + 0] = e;
                wsi[WS_META + 4 + nch*4 + 1] = sOff[e] + s;
                wsi[WS_META + 4 + nch*4 + 2] = len;
                wsi[WS_META + 4 + nch*4 + 3] = 0;
                nch++;
            }
        }
        for(int e = 0; e < 6; e++){
            wsi[WS_META + 4 + nch*4 + 0] = e;
            wsi[WS_META + 4 + nch*4 + 1] = 0;
            wsi[WS_META + 4 + nch*4 + 2] = 4;
            wsi[WS_META + 4 + nch*4 + 3] = 1;
            nch++;
        }
        wsi[WS_META] = nch;
    }
}

// ---------------- k3: grouped hstat GEMM via MFMA ----------------
#define PADK 264
__global__ __launch_bounds__(512) void k3_hstat(const u16* __restrict__ uws,
        const float* __restrict__ b1, float* __restrict__ ws){
    __shared__ u16 sX[64 * PADK];
    __shared__ int sRowB[64];
    int c = blockIdx.x, tid = threadIdx.x;
    int* wsi = (int*)ws;
    int nch = wsi[WS_META];
    if(c >= nch) return;
    int e    = wsi[WS_META + 4 + c*4 + 0];
    int start= wsi[WS_META + 4 + c*4 + 1];
    int len  = wsi[WS_META + 4 + c*4 + 2];
    int aux  = wsi[WS_META + 4 + c*4 + 3];
    if(tid < 64) sRowB[tid] = (tid < len) ? (aux ? tid : wsi[WS_PERM + start + tid]) : -1;

    int w = tid >> 6, l = tid & 63, lr = l & 15, lk = (l >> 4) * 8;
    const u16* w1T = uws + U_W1T;
    f32x4 accF[4][4];
    #pragma unroll
    for(int nt = 0; nt < 4; nt++){
        float bv = b1[e*512 + w*64 + nt*16 + lr];
        #pragma unroll
        for(int mt = 0; mt < 4; mt++){ f32x4 z = {bv, bv, bv, bv}; accF[mt][nt] = z; }
    }
    for(int sl = 0; sl < 4; sl++){
        __syncthreads();
        {   // stage X slice [64 rows][256 k] -> bf16
            int r = tid >> 3, c0 = (tid & 7) * 32;
            int b_r = sRowB[r];
            #pragma unroll
            for(int i = 0; i < 8; i++){
                int k = sl*256 + c0 + i*4;
                f32x4 v = {0.f, 0.f, 0.f, 0.f};
                if(b_r >= 0){
                    const float* p = (k < 512) ? &ws[WS_GCTX + b_r*512 + k]
                                               : &ws[WS_TEMB + b_r*512 + (k - 512)];
                    v = *(const f32x4*)p;
                }
                u16x4 pk; pk.x = f2bf(v.x); pk.y = f2bf(v.y); pk.z = f2bf(v.z); pk.w = f2bf(v.w);
                *(u16x4*)&sX[r*PADK + c0 + i*4] = pk;
            }
        }
        __syncthreads();
        for(int kt = 0; kt < 8; kt++){
            s16x8 av[4];
            #pragma unroll
            for(int mt = 0; mt < 4; mt++)
                av[mt] = *(const s16x8*)&sX[(mt*16 + lr)*PADK + kt*32 + lk];
            #pragma unroll
            for(int nt = 0; nt < 4; nt++){
                int col = w*64 + nt*16 + lr;
                size_t kg = 64 + sl*256 + kt*32 + lk;
                s16x8 bv = *(const s16x8*)&w1T[((size_t)e*512 + col)*1088 + kg];
                #pragma unroll
                for(int mt = 0; mt < 4; mt++) mfma16(accF[mt][nt], av[mt], bv);
            }
        }
    }
    #pragma unroll
    for(int mt = 0; mt < 4; mt++){
        #pragma unroll
        for(int rg = 0; rg < 4; rg++){
            int r = mt*16 + (l >> 4)*4 + rg;
            int b_r = sRowB[r];
            if(b_r < 0) continue;
            float* dst = aux ? &ws[WS_HSTAT2 + (e*4 + b_r)*512] : &ws[WS_HSTAT + b_r*512];
            #pragma unroll
            for(int nt = 0; nt < 4; nt++)
                dst[w*64 + nt*16 + lr] = accF[mt][nt][rg];
        }
    }
}

// ---------------- k4: per-sample FFN via MFMA ----------------
#define PADN 72
#define PADH 520
template<int STORE>
__global__ __launch_bounds__(512) void k4_ffn(const float* __restrict__ fut,
        const float* __restrict__ eps, const int* __restrict__ t_arr,
        const u16* __restrict__ uws, const float* __restrict__ b2,
        float* __restrict__ ws){
    __shared__ u16 sN[64 * PADN];
    __shared__ u16 sH[64 * PADH];
    __shared__ float sHs[512];
    __shared__ float sRed[8];
    int tid = threadIdx.x;
    int* wsi = (int*)ws;
    int b, e;
    if(STORE){ e = blockIdx.x >> 2; b = blockIdx.x & 3; }
    else     { b = blockIdx.x; e = wsi[WS_SELECTED + b]; }
    sHs[tid] = STORE ? ws[WS_HSTAT2 + (e*4 + b)*512 + tid] : ws[WS_HSTAT + b*512 + tid];
    int tv = t_arr[b];
    float ab = ws[WS_ALPHAS + tv];
    float sa = sqrtf(ab), sb = sqrtf(1.0f - ab);
    {   // noisy -> bf16 LDS
        int r = tid >> 3, c0 = (tid & 7) * 8;
        const f32x4* pf = (const f32x4*)&fut[((size_t)b*64 + r)*64 + c0];
        const f32x4* pe = (const f32x4*)&eps[((size_t)b*64 + r)*64 + c0];
        f32x4 f0 = pf[0], f1 = pf[1], e0 = pe[0], e1 = pe[1];
        u16x4 p0, p1;
        p0.x = f2bf(sa*f0.x + sb*e0.x); p0.y = f2bf(sa*f0.y + sb*e0.y);
        p0.z = f2bf(sa*f0.z + sb*e0.z); p0.w = f2bf(sa*f0.w + sb*e0.w);
        p1.x = f2bf(sa*f1.x + sb*e1.x); p1.y = f2bf(sa*f1.y + sb*e1.y);
        p1.z = f2bf(sa*f1.z + sb*e1.z); p1.w = f2bf(sa*f1.w + sb*e1.w);
        *(u16x4*)&sN[r*PADN + c0]     = p0;
        *(u16x4*)&sN[r*PADN + c0 + 4] = p1;
    }
    __syncthreads();
    int w = tid >> 6, l = tid & 63, lr = l & 15, lk = (l >> 4) * 8;
    const u16* w1T = uws + U_W1T;
    const u16* w2T = uws + U_W2T;
    // h-head: h[64 tf][512 j], K=64. wave w owns j-cols [w*64, w*64+64)
    f32x4 hacc[4][4];
    float hb[4];
    s16x8 bw[4][2];
    #pragma unroll
    for(int nt = 0; nt < 4; nt++){
        int col = w*64 + nt*16 + lr;
        hb[nt] = sHs[col];
        bw[nt][0] = *(const s16x8*)&w1T[((size_t)e*512 + col)*1088 + lk];
        bw[nt][1] = *(const s16x8*)&w1T[((size_t)e*512 + col)*1088 + 32 + lk];
    }
    #pragma unroll
    for(int mt = 0; mt < 4; mt++){
        s16x8 a0 = *(const s16x8*)&sN[(mt*16 + lr)*PADN + lk];
        s16x8 a1 = *(const s16x8*)&sN[(mt*16 + lr)*PADN + 32 + lk];
        #pragma unroll
        for(int nt = 0; nt < 4; nt++){
            f32x4 acc = {hb[nt], hb[nt], hb[nt], hb[nt]};
            mfma16(acc, a0, bw[nt][0]);
            mfma16(acc, a1, bw[nt][1]);
            hacc[mt][nt] = acc;
        }
    }
    #pragma unroll
    for(int mt = 0; mt < 4; mt++)
        #pragma unroll
        for(int nt = 0; nt < 4; nt++){
            int col = w*64 + nt*16 + lr;
            #pragma unroll
            for(int rg = 0; rg < 4; rg++){
                int row = mt*16 + (l >> 4)*4 + rg;
                sH[row*PADH + col] = f2bf(gelu_f(hacc[mt][nt][rg]));
            }
        }
    __syncthreads();
    // out: out[64 tf][64 f], K=512. wave w: mt_o = w>>1, nt pair = (w&1)*2..+1
    int mt_o = w >> 1, ntp = (w & 1) * 2;
    f32x4 oacc[2];
    #pragma unroll
    for(int i = 0; i < 2; i++){
        float bz = b2[e*64 + (ntp + i)*16 + lr];
        f32x4 z = {bz, bz, bz, bz}; oacc[i] = z;
    }
    for(int ks = 0; ks < 16; ks++){
        s16x8 a = *(const s16x8*)&sH[(mt_o*16 + lr)*PADH + ks*32 + lk];
        #pragma unroll
        for(int i = 0; i < 2; i++){
            s16x8 bb = *(const s16x8*)&w2T[((size_t)e*64 + (ntp + i)*16 + lr)*512 + ks*32 + lk];
            mfma16(oacc[i], a, bb);
        }
    }
    if(STORE){
        #pragma unroll
        for(int i = 0; i < 2; i++)
            #pragma unroll
            for(int rg = 0; rg < 4; rg++){
                int row = mt_o*16 + (l >> 4)*4 + rg;
                int col = (ntp + i)*16 + lr;
                ws[WS_OUTSUB + (e*4 + b)*4096 + row*64 + col] = oacc[i][rg];
            }
    } else {
        float ls = 0.f;
        #pragma unroll
        for(int i = 0; i < 2; i++)
            #pragma unroll
            for(int rg = 0; rg < 4; rg++){
                int row = mt_o*16 + (l >> 4)*4 + rg;
                int col = (ntp + i)*16 + lr;
                float d = oacc[i][rg] - eps[((size_t)b*64 + row)*64 + col];
                ls += d*d;
            }
        #pragma unroll
        for(int off = 32; off > 0; off >>= 1) ls += __shfl_down(ls, off);
        if(l == 0) sRed[w] = ls;
        __syncthreads();
        if(tid == 0){
            float s = 0.f;
            #pragma unroll
            for(int q = 0; q < 8; q++) s += sRed[q];
            const float pw[3] = {1.f, 5.f, 5.f};
            ws[WS_LOSSB + b] = (s * (1.0f/4096.0f)) * pw[e % 3];
        }
    }
}

// ---------------- k5a: chain (7) + smooth (6) partials ----------------
__global__ __launch_bounds__(256) void k5a_parts(float* __restrict__ ws){
    __shared__ float red[256];
    int bid = blockIdx.x, tid = threadIdx.x;
    float s = 0.f;
    if(bid < 7){
        const int pa[7] = {0,1,3,4,0,1,2};
        const int pb[7] = {1,2,4,5,3,4,5};
        const float* A  = &ws[WS_OUTSUB + pa[bid]*16384];
        const float* Bp = &ws[WS_OUTSUB + pb[bid]*16384];
        for(int i = tid; i < 4096; i += 256){
            f32x4 a = *(const f32x4*)&A[i*4];
            f32x4 c = *(const f32x4*)&Bp[i*4];
            f32x4 d = a - c;
            s += d.x*d.x + d.y*d.y + d.z*d.z + d.w*d.w;
        }
        s *= (1.0f/16384.0f);
    } else {
        int e = bid - 7;
        const float* O = &ws[WS_OUTSUB + e*16384];
        for(int i = tid; i < 4*63*16; i += 256){
            int sm = i / (63*16); int r = i % (63*16);
            int tf = r / 16; int f4 = (r % 16) * 4;
            f32x4 a = *(const f32x4*)&O[(sm*64 + tf + 1)*64 + f4];
            f32x4 c = *(const f32x4*)&O[(sm*64 + tf)*64 + f4];
            f32x4 d = a - c;
            s += d.x*d.x + d.y*d.y + d.z*d.z + d.w*d.w;
        }
        s *= (1.0f/16128.0f) * 0.5f;
    }
    red[tid] = s;
    __syncthreads();
    for(int st = 128; st > 0; st >>= 1){
        if(tid < st) red[tid] += red[tid + st];
        __syncthreads();
    }
    if(tid == 0) ws[WS_PARTS + bid] = red[0];
}

// ---------------- k5b: finalize ----------------
__global__ __launch_bounds__(512) void k5b_final(float* __restrict__ ws, float* __restrict__ out){
    __shared__ float rA[512], rB[512];
    int tid = threadIdx.x;
    int* wsi = (int*)ws;
    int sel = wsi[WS_SELECTED + tid];
    // weighted loss mean
    rA[tid] = ws[WS_LOSSB + tid];
    __syncthreads();
    for(int st = 256; st > 0; st >>= 1){ if(tid < st) rA[tid] += rA[tid + st]; __syncthreads(); }
    float total = 0.f;
    if(tid == 0){
        total = rA[0] * (1.0f/512.0f);
        float reg = 0.f;
        for(int p = 0; p < 13; p++) reg += ws[WS_PARTS + p];
        total += 0.01f * reg;
    }
    __syncthreads();
    // load balance: sum over e of f_e * P_e
    float lb = 0.f;
    for(int e = 0; e < 6; e++){
        rA[tid] = (sel == e) ? 1.f : 0.f;
        rB[tid] = ws[WS_PROBS + tid*6 + e];
        __syncthreads();
        for(int st = 256; st > 0; st >>= 1){
            if(tid < st){ rA[tid] += rA[tid + st]; rB[tid] += rB[tid + st]; }
            __syncthreads();
        }
        if(tid == 0) lb += (rA[0] * (1.0f/512.f)) * (rB[0] * (1.0f/512.f));
        __syncthreads();
    }
    if(tid == 0) out[0] = total + 0.01f * 6.0f * lb;
}

extern "C" void kernel_launch(void* const* d_in, const int* in_sizes, int n_in,
                              void* d_out, int out_size, void* d_ws, size_t ws_size,
                              hipStream_t stream){
    const float* obs  = (const float*)d_in[0];
    const float* fut  = (const float*)d_in[1];
    const float* stat = (const float*)d_in[2];
    const float* eps  = (const float*)d_in[3];
    const int*   phase= (const int*)d_in[4];
    const int*   t    = (const int*)d_in[5];
    const float* Wenc = (const float*)d_in[6];
    const float* benc = (const float*)d_in[7];
    const float* Wstat= (const float*)d_in[8];
    const float* Wr   = (const float*)d_in[9];
    const float* br   = (const float*)d_in[10];
    const float* W1   = (const float*)d_in[11];
    const float* b1   = (const float*)d_in[12];
    const float* W2   = (const float*)d_in[13];
    const float* b2   = (const float*)d_in[14];
    float* ws  = (float*)d_ws;
    u16*   uws = (u16*)((char*)d_ws + WS_U16BYTE);
    float* out = (float*)d_out;

    k0_init<<<1, 256, 0, stream>>>(ws);
    k0T<<<3488, 256, 0, stream>>>(Wenc, W1, W2, uws);
    k1_enc_mfma<<<512, 512, 0, stream>>>(obs, stat, Wstat, benc, uws, ws);
    k2_router<<<512, 64, 0, stream>>>(Wr, br, phase, t, ws);
    k2b_group<<<1, 512, 0, stream>>>(ws);
    k3_hstat<<<20, 512, 0, stream>>>(uws, b1, ws);
    k4_ffn<0><<<512, 512, 0, stream>>>(fut, eps, t, uws, b2, ws);
    k4_ffn<1><<<24, 512, 0, stream>>>(fut, eps, t, uws, b2, ws);
    k5a_parts<<<13, 256, 0, stream>>>(ws);
    k5b_final<<<1, 512, 0, stream>>>(ws, out);
}

// Round 3
// 140.176 us; speedup vs baseline: 5.7005x; 1.6372x over previous
//
#include <hip/hip_runtime.h>

typedef float  f32x4 __attribute__((ext_vector_type(4)));
typedef short  s16x8 __attribute__((ext_vector_type(8)));
typedef unsigned short u16;
typedef u16    u16x4 __attribute__((ext_vector_type(4)));

#define TIMESTEPS 1000

// ---- ws float-offset map ----
#define WS_ALPHAS   0        // 1000 f
#define WS_FREQS    1024     // 256 f
#define WS_PROBS    1536     // 512*6 f
#define WS_SELECTED 4608     // 512 int
#define WS_LOSSB    5632     // 512 f
#define WS_META     6144     // int: [0]=nch, entries (e,start,len,aux) from 6148
#define WS_PERM     6400     // 512 int
#define WS_PARTS    7168     // 13 f
#define WS_GCTX     8192     // 512*512 f   (k1 partial q=0, then combined by k2)
#define WS_TEMB     270336   // 512*512 f
#define WS_HSTAT    532480   // 512*512 f   (k1 partial q=1, then overwritten by k3)
#define WS_HSTAT2   794624   // 6*4*512 f
#define WS_OUTSUB   806912   // 6*4*64*64 f
#define WS_U16BYTE  3620864  // byte offset of u16 region (16B aligned)
// u16-offsets inside u16 region
#define U_WENCT     0        // 512*64
#define U_W1T       32768    // 6*512*1088
#define U_W2T       3375104  // 6*64*512

__device__ __forceinline__ u16 f2bf(float x){
    unsigned u = __builtin_bit_cast(unsigned, x);
    unsigned r = (u + 0x7FFFu + ((u >> 16) & 1u)) >> 16;
    return (u16)r;
}

__device__ __forceinline__ float gelu_f(float x){
    // x*(1 - 1/(exp2(2u/ln2)+1)), u = 0.79788456*(x + 0.044715 x^3)
    float x2 = x * x;
    float t  = x * fmaf(0.035677408136f, x2, 0.7978845608028654f);
    float ex = __builtin_amdgcn_exp2f(t * 2.885390081777927f);
    float r  = __builtin_amdgcn_rcpf(ex + 1.0f);
    return fmaf(-x, r, x);
}

__device__ __forceinline__ void mfma16(f32x4& c, s16x8 a, s16x8 b){
    asm volatile("v_mfma_f32_16x16x32_bf16 %0, %1, %2, %0" : "+v"(c) : "v"(a), "v"(b));
}

// ---------------- k0T: weight transposes to bf16 + alphas/freq init ----------------
__global__ __launch_bounds__(256) void k0T(const float* __restrict__ Wenc,
                                           const float* __restrict__ W1,
                                           const float* __restrict__ W2,
                                           u16* __restrict__ uws,
                                           float* __restrict__ ws){
    __shared__ float sT[32][33];
    __shared__ float sp[256];
    int bid = blockIdx.x, tid = threadIdx.x;
    const int t1 = 6*34*16, t2 = t1 + 6*16*2, t3 = t2 + 2*16;
    if(bid == t3){
        // freqs
        for(int k = tid; k < 256; k += 256)
            ws[WS_FREQS + k] = expf(-logf(10000.0f) * (float)k / 256.0f);
        // alphas_bar: chunked product scan (4 elems/thread)
        float p = 1.f;
        #pragma unroll
        for(int r = 0; r < 4; r++){
            int i = tid*4 + r;
            if(i < TIMESTEPS){
                float beta = 0.0001f + (0.02f - 0.0001f) * ((float)i / 999.0f);
                p *= (1.0f - beta);
            }
        }
        sp[tid] = p;
        __syncthreads();
        for(int st = 1; st < 256; st <<= 1){
            float v = (tid >= st) ? sp[tid - st] : 1.0f;
            __syncthreads();
            sp[tid] *= v;
            __syncthreads();
        }
        float run = (tid == 0) ? 1.0f : sp[tid - 1];
        for(int r = 0; r < 4; r++){
            int i = tid*4 + r;
            if(i < TIMESTEPS){
                float beta = 0.0001f + (0.02f - 0.0001f) * ((float)i / 999.0f);
                run *= (1.0f - beta);
                ws[WS_ALPHAS + i] = run;
            }
        }
        return;
    }
    const float* src; u16* dst; int K, J, kt, jt;
    if(bid < t1){
        int e = bid / 544, r = bid % 544; kt = r / 16; jt = r % 16;
        src = W1 + (size_t)e*1088*512; dst = uws + U_W1T + (size_t)e*512*1088; K = 1088; J = 512;
    } else if(bid < t2){
        int r = bid - t1; int e = r / 32; r %= 32; kt = r / 2; jt = r % 2;
        src = W2 + (size_t)e*512*64; dst = uws + U_W2T + (size_t)e*64*512; K = 512; J = 64;
    } else {
        int r = bid - t2; kt = r / 16; jt = r % 16;
        src = Wenc; dst = uws + U_WENCT; K = 64; J = 512;
    }
    int ty = tid >> 5, tx = tid & 31;
    #pragma unroll
    for(int i = 0; i < 4; i++)
        sT[ty + i*8][tx] = src[(size_t)(kt*32 + ty + i*8)*J + jt*32 + tx];
    __syncthreads();
    #pragma unroll
    for(int i = 0; i < 4; i++)
        dst[(size_t)(jt*32 + ty + i*8)*K + kt*32 + tx] = f2bf(sT[tx][ty + i*8]);
}

// ---------------- k1: encoder via MFMA, 2-way row split ----------------
#define PADX 72
__global__ __launch_bounds__(512) void k1_enc_mfma(const float* __restrict__ obs,
        const float* __restrict__ stat, const float* __restrict__ Wstat,
        const float* __restrict__ benc, const u16* __restrict__ uws,
        float* __restrict__ ws){
    __shared__ u16  sX[128 * PADX];
    __shared__ float sBias[512];
    __shared__ float sStat[32];
    int bid = blockIdx.x, b = bid >> 1, q = bid & 1, tid = threadIdx.x;
    if(tid < 32) sStat[tid] = stat[b*32 + tid];
    {   // stage 128 rows x 64 cols -> bf16
        int row = tid >> 2, c0 = (tid & 3) * 16;
        const f32x4* src = (const f32x4*)&obs[((size_t)(b*256 + q*128 + row))*64 + c0];
        u16* dst = &sX[row*PADX + c0];
        #pragma unroll
        for(int i = 0; i < 4; i++){
            f32x4 v = src[i];
            u16x4 pk; pk.x = f2bf(v.x); pk.y = f2bf(v.y); pk.z = f2bf(v.z); pk.w = f2bf(v.w);
            *(u16x4*)(dst + i*4) = pk;
        }
    }
    __syncthreads();
    {   // per-column bias = benc + stat@Wstat
        float v = benc[tid];
        #pragma unroll 8
        for(int s = 0; s < 32; s++) v += sStat[s] * Wstat[s*512 + tid];
        sBias[tid] = v;
    }
    __syncthreads();
    int w = tid >> 6, l = tid & 63, lr = l & 15, lk = (l >> 4) * 8;
    const u16* wencT = uws + U_WENCT;
    s16x8 bf[4][2];
    float bias[4];
    #pragma unroll
    for(int n = 0; n < 4; n++){
        int col = w*64 + n*16 + lr;
        bf[n][0] = *(const s16x8*)&wencT[col*64 + lk];
        bf[n][1] = *(const s16x8*)&wencT[col*64 + 32 + lk];
        bias[n]  = sBias[col];
    }
    float cac[4] = {0.f, 0.f, 0.f, 0.f};
    for(int mt = 0; mt < 8; mt++){
        s16x8 a0 = *(const s16x8*)&sX[(mt*16 + lr)*PADX + lk];
        s16x8 a1 = *(const s16x8*)&sX[(mt*16 + lr)*PADX + 32 + lk];
        #pragma unroll
        for(int n = 0; n < 4; n++){
            f32x4 acc = {bias[n], bias[n], bias[n], bias[n]};
            mfma16(acc, a0, bf[n][0]);
            mfma16(acc, a1, bf[n][1]);
            cac[n] += gelu_f(acc.x) + gelu_f(acc.y) + gelu_f(acc.z) + gelu_f(acc.w);
        }
    }
    #pragma unroll
    for(int n = 0; n < 4; n++){
        cac[n] += __shfl_xor(cac[n], 16);
        cac[n] += __shfl_xor(cac[n], 32);
    }
    float* pdst = q ? &ws[WS_HSTAT + b*512] : &ws[WS_GCTX + b*512];
    if(l < 16){
        #pragma unroll
        for(int n = 0; n < 4; n++)
            pdst[w*64 + n*16 + l] = cac[n];   // raw partial sum; k2 scales
    }
}

// ---------------- k2: combine partials + router + selection + t-embedding ----------------
__global__ __launch_bounds__(64) void k2_router(const float* __restrict__ Wr,
        const float* __restrict__ br, const int* __restrict__ phase,
        const int* __restrict__ t_arr, float* __restrict__ ws){
    int b = blockIdx.x, lane = threadIdx.x;
    float acc[6] = {0,0,0,0,0,0};
    int tv = t_arr[b];
    for(int k = 0; k < 8; k++){
        int d = k*64 + lane;
        float gv = (ws[WS_GCTX + b*512 + d] + ws[WS_HSTAT + b*512 + d]) * (1.0f/256.0f);
        ws[WS_GCTX + b*512 + d] = gv;
        #pragma unroll
        for(int e = 0; e < 6; e++) acc[e] += gv * Wr[d*6 + e];
        float fr = ws[WS_FREQS + (d & 255)];
        float a = (float)tv * fr;
        ws[WS_TEMB + b*512 + d] = (d < 256) ? sinf(a) : cosf(a);
    }
    #pragma unroll
    for(int off = 32; off > 0; off >>= 1)
        #pragma unroll
        for(int e = 0; e < 6; e++) acc[e] += __shfl_down(acc[e], off);
    if(lane == 0){
        float logit[6], mx = -1e30f;
        #pragma unroll
        for(int e = 0; e < 6; e++){ logit[e] = acc[e] + br[e]; mx = fmaxf(mx, logit[e]); }
        float s = 0.f, p[6];
        #pragma unroll
        for(int e = 0; e < 6; e++){ p[e] = expf(logit[e] - mx); s += p[e]; }
        float inv = 1.0f / s;
        #pragma unroll
        for(int e = 0; e < 6; e++) ws[WS_PROBS + b*6 + e] = p[e] * inv;
        int ph = phase[b];
        int sel = ph + ((logit[ph + 3] > logit[ph]) ? 3 : 0);
        ((int*)ws)[WS_SELECTED + b] = sel;
    }
}

// ---------------- k2b: group samples by expert (ballot-based, deterministic) ----------------
__global__ __launch_bounds__(512) void k2b_group(float* __restrict__ ws){
    __shared__ int sCnt[8][6];
    __shared__ int sBase[8][6];
    __shared__ int sTot[6], sOff[6];
    int tid = threadIdx.x, w = tid >> 6, l = tid & 63;
    int* wsi = (int*)ws;
    int sv = wsi[WS_SELECTED + tid];
    unsigned long long mym = 0;
    #pragma unroll
    for(int e = 0; e < 6; e++){
        unsigned long long m = __ballot(sv == e);
        if(l == 0) sCnt[w][e] = __popcll(m);
        if(sv == e) mym = m;
    }
    __syncthreads();
    if(tid == 0){
        int o = 0;
        for(int e = 0; e < 6; e++){
            sOff[e] = o;
            for(int ww = 0; ww < 8; ww++){ sBase[ww][e] = o; o += sCnt[ww][e]; }
            sTot[e] = o - sOff[e];
        }
        int nch = 0;
        for(int e = 0; e < 6; e++){
            for(int s = 0; s < sTot[e]; s += 64){
                int len = sTot[e] - s; if(len > 64) len = 64;
                wsi[WS_META + 4 + nch*4 + 0] = e;
                wsi[WS_META + 4 + nch*4 + 1] = sOff[e] + s;
                wsi[WS_META + 4 + nch*4 + 2] = len;
                wsi[WS_META + 4 + nch*4 + 3] = 0;
                nch++;
            }
        }
        for(int e = 0; e < 6; e++){
            wsi[WS_META + 4 + nch*4 + 0] = e;
            wsi[WS_META + 4 + nch*4 + 1] = 0;
            wsi[WS_META + 4 + nch*4 + 2] = 4;
            wsi[WS_META + 4 + nch*4 + 3] = 1;
            nch++;
        }
        wsi[WS_META] = nch;
    }
    __syncthreads();
    int rank = __popcll(mym & ((1ull << l) - 1ull));
    wsi[WS_PERM + sBase[w][sv] + rank] = tid;
}

// ---------------- k3: grouped hstat GEMM via MFMA ----------------
#define PADK 264
__global__ __launch_bounds__(512) void k3_hstat(const u16* __restrict__ uws,
        const float* __restrict__ b1, float* __restrict__ ws){
    __shared__ u16 sX[64 * PADK];
    __shared__ int sRowB[64];
    int c = blockIdx.x, tid = threadIdx.x;
    int* wsi = (int*)ws;
    int nch = wsi[WS_META];
    if(c >= nch) return;
    int e    = wsi[WS_META + 4 + c*4 + 0];
    int start= wsi[WS_META + 4 + c*4 + 1];
    int len  = wsi[WS_META + 4 + c*4 + 2];
    int aux  = wsi[WS_META + 4 + c*4 + 3];
    if(tid < 64) sRowB[tid] = (tid < len) ? (aux ? tid : wsi[WS_PERM + start + tid]) : -1;

    int w = tid >> 6, l = tid & 63, lr = l & 15, lk = (l >> 4) * 8;
    const u16* w1T = uws + U_W1T;
    f32x4 accF[4][4];
    #pragma unroll
    for(int nt = 0; nt < 4; nt++){
        float bv = b1[e*512 + w*64 + nt*16 + lr];
        #pragma unroll
        for(int mt = 0; mt < 4; mt++){ f32x4 z = {bv, bv, bv, bv}; accF[mt][nt] = z; }
    }
    for(int sl = 0; sl < 4; sl++){
        __syncthreads();
        {   // stage X slice [64 rows][256 k] -> bf16
            int r = tid >> 3, c0 = (tid & 7) * 32;
            int b_r = sRowB[r];
            #pragma unroll
            for(int i = 0; i < 8; i++){
                int k = sl*256 + c0 + i*4;
                f32x4 v = {0.f, 0.f, 0.f, 0.f};
                if(b_r >= 0){
                    const float* p = (k < 512) ? &ws[WS_GCTX + b_r*512 + k]
                                               : &ws[WS_TEMB + b_r*512 + (k - 512)];
                    v = *(const f32x4*)p;
                }
                u16x4 pk; pk.x = f2bf(v.x); pk.y = f2bf(v.y); pk.z = f2bf(v.z); pk.w = f2bf(v.w);
                *(u16x4*)&sX[r*PADK + c0 + i*4] = pk;
            }
        }
        __syncthreads();
        for(int kt = 0; kt < 8; kt++){
            s16x8 av[4];
            #pragma unroll
            for(int mt = 0; mt < 4; mt++)
                av[mt] = *(const s16x8*)&sX[(mt*16 + lr)*PADK + kt*32 + lk];
            #pragma unroll
            for(int nt = 0; nt < 4; nt++){
                int col = w*64 + nt*16 + lr;
                size_t kg = 64 + sl*256 + kt*32 + lk;
                s16x8 bv = *(const s16x8*)&w1T[((size_t)e*512 + col)*1088 + kg];
                #pragma unroll
                for(int mt = 0; mt < 4; mt++) mfma16(accF[mt][nt], av[mt], bv);
            }
        }
    }
    #pragma unroll
    for(int mt = 0; mt < 4; mt++){
        #pragma unroll
        for(int rg = 0; rg < 4; rg++){
            int r = mt*16 + (l >> 4)*4 + rg;
            int b_r = sRowB[r];
            if(b_r < 0) continue;
            float* dst = aux ? &ws[WS_HSTAT2 + (e*4 + b_r)*512] : &ws[WS_HSTAT + b_r*512];
            #pragma unroll
            for(int nt = 0; nt < 4; nt++)
                dst[w*64 + nt*16 + lr] = accF[mt][nt][rg];
        }
    }
}

// ---------------- k4: per-sample FFN via MFMA (loss mode + store mode in one grid) ----------------
#define PADN 72
#define PADH 520
__global__ __launch_bounds__(512) void k4_ffn(const float* __restrict__ fut,
        const float* __restrict__ eps, const int* __restrict__ t_arr,
        const u16* __restrict__ uws, const float* __restrict__ b2,
        float* __restrict__ ws){
    __shared__ u16 sN[64 * PADN];
    __shared__ u16 sH[64 * PADH];
    __shared__ float sHs[512];
    __shared__ float sRed[8];
    int tid = threadIdx.x, bid = blockIdx.x;
    int* wsi = (int*)ws;
    int b, e, store;
    if(bid < 512){ b = bid; e = wsi[WS_SELECTED + b]; store = 0; }
    else { int r = bid - 512; e = r >> 2; b = r & 3; store = 1; }
    sHs[tid] = store ? ws[WS_HSTAT2 + (e*4 + b)*512 + tid] : ws[WS_HSTAT + b*512 + tid];
    int tv = t_arr[b];
    float ab = ws[WS_ALPHAS + tv];
    float sa = sqrtf(ab), sb = sqrtf(1.0f - ab);
    {   // noisy -> bf16 LDS
        int r = tid >> 3, c0 = (tid & 7) * 8;
        const f32x4* pf = (const f32x4*)&fut[((size_t)b*64 + r)*64 + c0];
        const f32x4* pe = (const f32x4*)&eps[((size_t)b*64 + r)*64 + c0];
        f32x4 f0 = pf[0], f1 = pf[1], e0 = pe[0], e1 = pe[1];
        u16x4 p0, p1;
        p0.x = f2bf(sa*f0.x + sb*e0.x); p0.y = f2bf(sa*f0.y + sb*e0.y);
        p0.z = f2bf(sa*f0.z + sb*e0.z); p0.w = f2bf(sa*f0.w + sb*e0.w);
        p1.x = f2bf(sa*f1.x + sb*e1.x); p1.y = f2bf(sa*f1.y + sb*e1.y);
        p1.z = f2bf(sa*f1.z + sb*e1.z); p1.w = f2bf(sa*f1.w + sb*e1.w);
        *(u16x4*)&sN[r*PADN + c0]     = p0;
        *(u16x4*)&sN[r*PADN + c0 + 4] = p1;
    }
    __syncthreads();
    int w = tid >> 6, l = tid & 63, lr = l & 15, lk = (l >> 4) * 8;
    const u16* w1T = uws + U_W1T;
    const u16* w2T = uws + U_W2T;
    // h-head: h[64 tf][512 j], K=64. wave w owns j-cols [w*64, w*64+64)
    f32x4 hacc[4][4];
    float hb[4];
    s16x8 bw[4][2];
    #pragma unroll
    for(int nt = 0; nt < 4; nt++){
        int col = w*64 + nt*16 + lr;
        hb[nt] = sHs[col];
        bw[nt][0] = *(const s16x8*)&w1T[((size_t)e*512 + col)*1088 + lk];
        bw[nt][1] = *(const s16x8*)&w1T[((size_t)e*512 + col)*1088 + 32 + lk];
    }
    #pragma unroll
    for(int mt = 0; mt < 4; mt++){
        s16x8 a0 = *(const s16x8*)&sN[(mt*16 + lr)*PADN + lk];
        s16x8 a1 = *(const s16x8*)&sN[(mt*16 + lr)*PADN + 32 + lk];
        #pragma unroll
        for(int nt = 0; nt < 4; nt++){
            f32x4 acc = {hb[nt], hb[nt], hb[nt], hb[nt]};
            mfma16(acc, a0, bw[nt][0]);
            mfma16(acc, a1, bw[nt][1]);
            hacc[mt][nt] = acc;
        }
    }
    #pragma unroll
    for(int mt = 0; mt < 4; mt++)
        #pragma unroll
        for(int nt = 0; nt < 4; nt++){
            int col = w*64 + nt*16 + lr;
            #pragma unroll
            for(int rg = 0; rg < 4; rg++){
                int row = mt*16 + (l >> 4)*4 + rg;
                sH[row*PADH + col] = f2bf(gelu_f(hacc[mt][nt][rg]));
            }
        }
    __syncthreads();
    // out: out[64 tf][64 f], K=512. wave w: mt group = (w>>2)*2, nt = w&3
    int mtg = (w >> 2) << 1;
    int nt  = w & 3;
    f32x4 oacc[2];
    {
        float bz = b2[e*64 + nt*16 + lr];
        f32x4 z = {bz, bz, bz, bz}; oacc[0] = z; oacc[1] = z;
    }
    for(int ks = 0; ks < 16; ks++){
        s16x8 bb = *(const s16x8*)&w2T[((size_t)e*64 + nt*16 + lr)*512 + ks*32 + lk];
        #pragma unroll
        for(int i = 0; i < 2; i++){
            s16x8 a = *(const s16x8*)&sH[((mtg + i)*16 + lr)*PADH + ks*32 + lk];
            mfma16(oacc[i], a, bb);
        }
    }
    if(store){
        #pragma unroll
        for(int i = 0; i < 2; i++)
            #pragma unroll
            for(int rg = 0; rg < 4; rg++){
                int row = (mtg + i)*16 + (l >> 4)*4 + rg;
                int col = nt*16 + lr;
                ws[WS_OUTSUB + (e*4 + b)*4096 + row*64 + col] = oacc[i][rg];
            }
    } else {
        float ls = 0.f;
        #pragma unroll
        for(int i = 0; i < 2; i++)
            #pragma unroll
            for(int rg = 0; rg < 4; rg++){
                int row = (mtg + i)*16 + (l >> 4)*4 + rg;
                int col = nt*16 + lr;
                float d = oacc[i][rg] - eps[((size_t)b*64 + row)*64 + col];
                ls += d*d;
            }
        #pragma unroll
        for(int off = 32; off > 0; off >>= 1) ls += __shfl_down(ls, off);
        if(l == 0) sRed[w] = ls;
        __syncthreads();
        if(tid == 0){
            float s = 0.f;
            #pragma unroll
            for(int q = 0; q < 8; q++) s += sRed[q];
            const float pw[3] = {1.f, 5.f, 5.f};
            ws[WS_LOSSB + b] = (s * (1.0f/4096.0f)) * pw[e % 3];
        }
    }
}

// ---------------- k5a: chain (7) + smooth (6) partials ----------------
__global__ __launch_bounds__(256) void k5a_parts(float* __restrict__ ws){
    __shared__ float red[256];
    int bid = blockIdx.x, tid = threadIdx.x;
    float s = 0.f;
    if(bid < 7){
        const int pa[7] = {0,1,3,4,0,1,2};
        const int pb[7] = {1,2,4,5,3,4,5};
        const float* A  = &ws[WS_OUTSUB + pa[bid]*16384];
        const float* Bp = &ws[WS_OUTSUB + pb[bid]*16384];
        for(int i = tid; i < 4096; i += 256){
            f32x4 a = *(const f32x4*)&A[i*4];
            f32x4 c = *(const f32x4*)&Bp[i*4];
            f32x4 d = a - c;
            s += d.x*d.x + d.y*d.y + d.z*d.z + d.w*d.w;
        }
        s *= (1.0f/16384.0f);
    } else {
        int e = bid - 7;
        const float* O = &ws[WS_OUTSUB + e*16384];
        for(int i = tid; i < 4*63*16; i += 256){
            int sm = i / (63*16); int r = i % (63*16);
            int tf = r / 16; int f4 = (r % 16) * 4;
            f32x4 a = *(const f32x4*)&O[(sm*64 + tf + 1)*64 + f4];
            f32x4 c = *(const f32x4*)&O[(sm*64 + tf)*64 + f4];
            f32x4 d = a - c;
            s += d.x*d.x + d.y*d.y + d.z*d.z + d.w*d.w;
        }
        s *= (1.0f/16128.0f) * 0.5f;
    }
    red[tid] = s;
    __syncthreads();
    for(int st = 128; st > 0; st >>= 1){
        if(tid < st) red[tid] += red[tid + st];
        __syncthreads();
    }
    if(tid == 0) ws[WS_PARTS + bid] = red[0];
}

// ---------------- k5b: finalize ----------------
__global__ __launch_bounds__(512) void k5b_final(float* __restrict__ ws, float* __restrict__ out){
    __shared__ float rA[512], rB[512];
    int tid = threadIdx.x;
    int* wsi = (int*)ws;
    int sel = wsi[WS_SELECTED + tid];
    rA[tid] = ws[WS_LOSSB + tid];
    __syncthreads();
    for(int st = 256; st > 0; st >>= 1){ if(tid < st) rA[tid] += rA[tid + st]; __syncthreads(); }
    float total = 0.f;
    if(tid == 0){
        total = rA[0] * (1.0f/512.0f);
        float reg = 0.f;
        for(int p = 0; p < 13; p++) reg += ws[WS_PARTS + p];
        total += 0.01f * reg;
    }
    __syncthreads();
    float lb = 0.f;
    for(int e = 0; e < 6; e++){
        rA[tid] = (sel == e) ? 1.f : 0.f;
        rB[tid] = ws[WS_PROBS + tid*6 + e];
        __syncthreads();
        for(int st = 256; st > 0; st >>= 1){
            if(tid < st){ rA[tid] += rA[tid + st]; rB[tid] += rB[tid + st]; }
            __syncthreads();
        }
        if(tid == 0) lb += (rA[0] * (1.0f/512.f)) * (rB[0] * (1.0f/512.f));
        __syncthreads();
    }
    if(tid == 0) out[0] = total + 0.01f * 6.0f * lb;
}

extern "C" void kernel_launch(void* const* d_in, const int* in_sizes, int n_in,
                              void* d_out, int out_size, void* d_ws, size_t ws_size,
                              hipStream_t stream){
    const float* obs  = (const float*)d_in[0];
    const float* fut  = (const float*)d_in[1];
    const float* stat = (const float*)d_in[2];
    const float* eps  = (const float*)d_in[3];
    const int*   phase= (const int*)d_in[4];
    const int*   t    = (const int*)d_in[5];
    const float* Wenc = (const float*)d_in[6];
    const float* benc = (const float*)d_in[7];
    const float* Wstat= (const float*)d_in[8];
    const float* Wr   = (const float*)d_in[9];
    const float* br   = (const float*)d_in[10];
    const float* W1   = (const float*)d_in[11];
    const float* b1   = (const float*)d_in[12];
    const float* W2   = (const float*)d_in[13];
    const float* b2   = (const float*)d_in[14];
    float* ws  = (float*)d_ws;
    u16*   uws = (u16*)((char*)d_ws + WS_U16BYTE);
    float* out = (float*)d_out;

    k0T<<<3489, 256, 0, stream>>>(Wenc, W1, W2, uws, ws);
    k1_enc_mfma<<<1024, 512, 0, stream>>>(obs, stat, Wstat, benc, uws, ws);
    k2_router<<<512, 64, 0, stream>>>(Wr, br, phase, t, ws);
    k2b_group<<<1, 512, 0, stream>>>(ws);
    k3_hstat<<<20, 512, 0, stream>>>(uws, b1, ws);
    k4_ffn<<<536, 512, 0, stream>>>(fut, eps, t, uws, b2, ws);
    k5a_parts<<<13, 256, 0, stream>>>(ws);
    k5b_final<<<1, 512, 0, stream>>>(ws, out);
}

// Round 4
// 109.451 us; speedup vs baseline: 7.3007x; 1.2807x over previous
//
#include <hip/hip_runtime.h>

typedef float  f32x4 __attribute__((ext_vector_type(4)));
typedef short  s16x8 __attribute__((ext_vector_type(8)));
typedef unsigned short u16;
typedef u16    u16x4 __attribute__((ext_vector_type(4)));

#define TIMESTEPS 1000

// ---- ws float-offset map ----
#define WS_ALPHAS   0        // 1000 f
#define WS_FREQS    1024     // 256 f
#define WS_PROBS    1536     // 512*6 f
#define WS_SELECTED 4608     // 512 int
#define WS_LOSSB    5632     // 512 f
#define WS_META     6144     // int: [0]=nch, triples (e,start,len) stride 4
#define WS_ROWSRC   6400     // 640 int
#define WS_ROWDST   7040     // 640 int (float-offset into ws, -1 = skip)
#define WS_PARTS    7680     // 13 f
#define WS_GCTX     8192     // 512*512 f   (k1 partial q=0; dead after k2)
#define WS_XC       270336   // reused region: 512*1024 bf16 (u16) = 512 KB
#define WS_HSTAT    532480   // 512*512 f   (k1 partial q=1, then overwritten by k3)
#define WS_HSTAT2   794624   // 6*4*512 f
#define WS_OUTSUB   806912   // 6*4*64*64 f
#define WS_U16BYTE  3620864  // byte offset of u16 weight region (16B aligned)
// u16-offsets inside u16 region
#define U_WENCT     0        // 512*64
#define U_W1T       32768    // 6*512*1088
#define U_W2T       3375104  // 6*64*512

__device__ __forceinline__ u16 f2bf(float x){
    unsigned u = __builtin_bit_cast(unsigned, x);
    unsigned r = (u + 0x7FFFu + ((u >> 16) & 1u)) >> 16;
    return (u16)r;
}

__device__ __forceinline__ float gelu_f(float x){
    float x2 = x * x;
    float t  = x * fmaf(0.035677408136f, x2, 0.7978845608028654f);
    float ex = __builtin_amdgcn_exp2f(t * 2.885390081777927f);
    float r  = __builtin_amdgcn_rcpf(ex + 1.0f);
    return fmaf(-x, r, x);
}

__device__ __forceinline__ void mfma16(f32x4& c, s16x8 a, s16x8 b){
    asm volatile("v_mfma_f32_16x16x32_bf16 %0, %1, %2, %0" : "+v"(c) : "v"(a), "v"(b));
}

// ---------------- k0T: weight transposes to bf16 + alphas/freq init ----------------
__global__ __launch_bounds__(256) void k0T(const float* __restrict__ Wenc,
                                           const float* __restrict__ W1,
                                           const float* __restrict__ W2,
                                           u16* __restrict__ uws,
                                           float* __restrict__ ws){
    __shared__ float sT[32][33];
    __shared__ float sp[256];
    int bid = blockIdx.x, tid = threadIdx.x;
    const int t1 = 6*34*16, t2 = t1 + 6*16*2, t3 = t2 + 2*16;
    if(bid == t3){
        for(int k = tid; k < 256; k += 256)
            ws[WS_FREQS + k] = expf(-logf(10000.0f) * (float)k / 256.0f);
        float p = 1.f;
        #pragma unroll
        for(int r = 0; r < 4; r++){
            int i = tid*4 + r;
            if(i < TIMESTEPS){
                float beta = 0.0001f + (0.02f - 0.0001f) * ((float)i / 999.0f);
                p *= (1.0f - beta);
            }
        }
        sp[tid] = p;
        __syncthreads();
        for(int st = 1; st < 256; st <<= 1){
            float v = (tid >= st) ? sp[tid - st] : 1.0f;
            __syncthreads();
            sp[tid] *= v;
            __syncthreads();
        }
        float run = (tid == 0) ? 1.0f : sp[tid - 1];
        for(int r = 0; r < 4; r++){
            int i = tid*4 + r;
            if(i < TIMESTEPS){
                float beta = 0.0001f + (0.02f - 0.0001f) * ((float)i / 999.0f);
                run *= (1.0f - beta);
                ws[WS_ALPHAS + i] = run;
            }
        }
        return;
    }
    const float* src; u16* dst; int K, J, kt, jt;
    if(bid < t1){
        int e = bid / 544, r = bid % 544; kt = r / 16; jt = r % 16;
        src = W1 + (size_t)e*1088*512; dst = uws + U_W1T + (size_t)e*512*1088; K = 1088; J = 512;
    } else if(bid < t2){
        int r = bid - t1; int e = r / 32; r %= 32; kt = r / 2; jt = r % 2;
        src = W2 + (size_t)e*512*64; dst = uws + U_W2T + (size_t)e*64*512; K = 512; J = 64;
    } else {
        int r = bid - t2; kt = r / 16; jt = r % 16;
        src = Wenc; dst = uws + U_WENCT; K = 64; J = 512;
    }
    int ty = tid >> 5, tx = tid & 31;
    #pragma unroll
    for(int i = 0; i < 4; i++)
        sT[ty + i*8][tx] = src[(size_t)(kt*32 + ty + i*8)*J + jt*32 + tx];
    __syncthreads();
    #pragma unroll
    for(int i = 0; i < 4; i++)
        dst[(size_t)(jt*32 + ty + i*8)*K + kt*32 + tx] = f2bf(sT[tx][ty + i*8]);
}

// ---------------- k1: encoder via MFMA, 2-way row split ----------------
#define PADX 72
__global__ __launch_bounds__(512) void k1_enc_mfma(const float* __restrict__ obs,
        const float* __restrict__ stat, const float* __restrict__ Wstat,
        const float* __restrict__ benc, const u16* __restrict__ uws,
        float* __restrict__ ws){
    __shared__ u16  sX[128 * PADX];
    __shared__ float sBias[512];
    __shared__ float sStat[32];
    int bid = blockIdx.x, b = bid >> 1, q = bid & 1, tid = threadIdx.x;
    if(tid < 32) sStat[tid] = stat[b*32 + tid];
    {
        int row = tid >> 2, c0 = (tid & 3) * 16;
        const f32x4* src = (const f32x4*)&obs[((size_t)(b*256 + q*128 + row))*64 + c0];
        u16* dst = &sX[row*PADX + c0];
        #pragma unroll
        for(int i = 0; i < 4; i++){
            f32x4 v = src[i];
            u16x4 pk; pk.x = f2bf(v.x); pk.y = f2bf(v.y); pk.z = f2bf(v.z); pk.w = f2bf(v.w);
            *(u16x4*)(dst + i*4) = pk;
        }
    }
    __syncthreads();
    {
        float v = benc[tid];
        #pragma unroll 8
        for(int s = 0; s < 32; s++) v += sStat[s] * Wstat[s*512 + tid];
        sBias[tid] = v;
    }
    __syncthreads();
    int w = tid >> 6, l = tid & 63, lr = l & 15, lk = (l >> 4) * 8;
    const u16* wencT = uws + U_WENCT;
    s16x8 bf[4][2];
    float bias[4];
    #pragma unroll
    for(int n = 0; n < 4; n++){
        int col = w*64 + n*16 + lr;
        bf[n][0] = *(const s16x8*)&wencT[col*64 + lk];
        bf[n][1] = *(const s16x8*)&wencT[col*64 + 32 + lk];
        bias[n]  = sBias[col];
    }
    float cac[4] = {0.f, 0.f, 0.f, 0.f};
    for(int mt = 0; mt < 8; mt++){
        s16x8 a0 = *(const s16x8*)&sX[(mt*16 + lr)*PADX + lk];
        s16x8 a1 = *(const s16x8*)&sX[(mt*16 + lr)*PADX + 32 + lk];
        #pragma unroll
        for(int n = 0; n < 4; n++){
            f32x4 acc = {bias[n], bias[n], bias[n], bias[n]};
            mfma16(acc, a0, bf[n][0]);
            mfma16(acc, a1, bf[n][1]);
            cac[n] += gelu_f(acc.x) + gelu_f(acc.y) + gelu_f(acc.z) + gelu_f(acc.w);
        }
    }
    #pragma unroll
    for(int n = 0; n < 4; n++){
        cac[n] += __shfl_xor(cac[n], 16);
        cac[n] += __shfl_xor(cac[n], 32);
    }
    float* pdst = q ? &ws[WS_HSTAT + b*512] : &ws[WS_GCTX + b*512];
    if(l < 16){
        #pragma unroll
        for(int n = 0; n < 4; n++)
            pdst[w*64 + n*16 + l] = cac[n];   // raw partial sum; k2 scales
    }
}

// ---------------- k2: combine partials + router + selection + XC(bf16) ----------------
__global__ __launch_bounds__(64) void k2_router(const float* __restrict__ Wr,
        const float* __restrict__ br, const int* __restrict__ phase,
        const int* __restrict__ t_arr, float* __restrict__ ws){
    int b = blockIdx.x, lane = threadIdx.x;
    float acc[6] = {0,0,0,0,0,0};
    int tv = t_arr[b];
    u16* XC = (u16*)(ws + WS_XC);
    for(int k = 0; k < 8; k++){
        int d = k*64 + lane;
        float gv = (ws[WS_GCTX + b*512 + d] + ws[WS_HSTAT + b*512 + d]) * (1.0f/256.0f);
        XC[b*1024 + d] = f2bf(gv);
        #pragma unroll
        for(int e = 0; e < 6; e++) acc[e] += gv * Wr[d*6 + e];
        float fr = ws[WS_FREQS + (d & 255)];
        float a = (float)tv * fr;
        XC[b*1024 + 512 + d] = f2bf((d < 256) ? sinf(a) : cosf(a));
    }
    #pragma unroll
    for(int off = 32; off > 0; off >>= 1)
        #pragma unroll
        for(int e = 0; e < 6; e++) acc[e] += __shfl_down(acc[e], off);
    if(lane == 0){
        float logit[6], mx = -1e30f;
        #pragma unroll
        for(int e = 0; e < 6; e++){ logit[e] = acc[e] + br[e]; mx = fmaxf(mx, logit[e]); }
        float s = 0.f, p[6];
        #pragma unroll
        for(int e = 0; e < 6; e++){ p[e] = expf(logit[e] - mx); s += p[e]; }
        float inv = 1.0f / s;
        #pragma unroll
        for(int e = 0; e < 6; e++) ws[WS_PROBS + b*6 + e] = p[e] * inv;
        int ph = phase[b];
        int sel = ph + ((logit[ph + 3] > logit[ph]) ? 3 : 0);
        ((int*)ws)[WS_SELECTED + b] = sel;
    }
}

// ---------------- k2b: build row list (loss rows + aux rows per expert section) ----------------
__global__ __launch_bounds__(512) void k2b_group(float* __restrict__ ws){
    __shared__ int sCnt[8][6];
    __shared__ int sBase[8][6];
    __shared__ int sSec[6], sTot[6];
    int tid = threadIdx.x, w = tid >> 6, l = tid & 63;
    int* wsi = (int*)ws;
    int sv = wsi[WS_SELECTED + tid];
    unsigned long long mym = 0;
    #pragma unroll
    for(int e = 0; e < 6; e++){
        unsigned long long m = __ballot(sv == e);
        if(l == 0) sCnt[w][e] = __popcll(m);
        if(sv == e) mym = m;
    }
    __syncthreads();
    if(tid == 0){
        int o = 0;
        for(int e = 0; e < 6; e++){
            sSec[e] = o;
            int t0 = 0;
            for(int ww = 0; ww < 8; ww++){ sBase[ww][e] = o; o += sCnt[ww][e]; t0 += sCnt[ww][e]; }
            sTot[e] = t0;
            o += 4;                       // reserve aux rows
        }
        int nch = 0;
        for(int e = 0; e < 6; e++){
            int len = sTot[e] + 4, st = sSec[e];
            for(int s = 0; s < len; s += 64){
                int cl = len - s; if(cl > 64) cl = 64;
                wsi[WS_META + 4 + nch*4 + 0] = e;
                wsi[WS_META + 4 + nch*4 + 1] = st + s;
                wsi[WS_META + 4 + nch*4 + 2] = cl;
                nch++;
            }
        }
        wsi[WS_META] = nch;
    }
    __syncthreads();
    int rank = __popcll(mym & ((1ull << l) - 1ull));
    int pos = sBase[w][sv] + rank;
    wsi[WS_ROWSRC + pos] = tid;
    wsi[WS_ROWDST + pos] = WS_HSTAT + tid*512;
    if(tid < 24){
        int e = tid >> 2, b = tid & 3;
        int pos2 = sSec[e] + sTot[e] + b;
        wsi[WS_ROWSRC + pos2] = b;
        wsi[WS_ROWDST + pos2] = WS_HSTAT2 + (e*4 + b)*512;
    }
}

// ---------------- k3: hstat GEMM, direct-global fragments, high parallelism ----------------
__global__ __launch_bounds__(256) void k3_hstat(const u16* __restrict__ uws,
        const float* __restrict__ b1, float* __restrict__ ws){
    __shared__ int sSrc[64], sDst[64];
    int bid = blockIdx.x, tid = threadIdx.x;
    int c = bid >> 3, jt = bid & 7;
    int* wsi = (int*)ws;
    if(c >= wsi[WS_META]) return;
    int e    = wsi[WS_META + 4 + c*4 + 0];
    int start= wsi[WS_META + 4 + c*4 + 1];
    int len  = wsi[WS_META + 4 + c*4 + 2];
    if(tid < 64){
        int ok = tid < len;
        sSrc[tid] = ok ? wsi[WS_ROWSRC + start + tid] : 0;
        sDst[tid] = ok ? wsi[WS_ROWDST + start + tid] : -1;
    }
    __syncthreads();
    int w = tid >> 6, l = tid & 63, lr = l & 15, lk = (l >> 4) * 8;
    int col = jt*64 + w*16 + lr;
    const u16* XC = (const u16*)(ws + WS_XC);
    const u16* rowA[4];
    #pragma unroll
    for(int mt = 0; mt < 4; mt++)
        rowA[mt] = XC + (size_t)sSrc[mt*16 + lr]*1024 + lk;
    const u16* bp = uws + U_W1T + ((size_t)e*512 + col)*1088 + 64 + lk;
    f32x4 acc[4];
    {
        float bv = b1[e*512 + col];
        f32x4 z = {bv, bv, bv, bv};
        #pragma unroll
        for(int mt = 0; mt < 4; mt++) acc[mt] = z;
    }
    #pragma unroll 4
    for(int ks = 0; ks < 32; ks++){
        s16x8 bb = *(const s16x8*)(bp + ks*32);
        s16x8 a0 = *(const s16x8*)(rowA[0] + ks*32);
        s16x8 a1 = *(const s16x8*)(rowA[1] + ks*32);
        s16x8 a2 = *(const s16x8*)(rowA[2] + ks*32);
        s16x8 a3 = *(const s16x8*)(rowA[3] + ks*32);
        mfma16(acc[0], a0, bb);
        mfma16(acc[1], a1, bb);
        mfma16(acc[2], a2, bb);
        mfma16(acc[3], a3, bb);
    }
    #pragma unroll
    for(int mt = 0; mt < 4; mt++){
        #pragma unroll
        for(int rg = 0; rg < 4; rg++){
            int r = mt*16 + (l >> 4)*4 + rg;
            int d = sDst[r];
            if(d >= 0) ws[d + col] = acc[mt][rg];
        }
    }
}

// ---------------- k4: per-sample FFN via MFMA (loss mode + store mode in one grid) ----------------
#define PADN 72
#define PADH 520
__global__ __launch_bounds__(512) void k4_ffn(const float* __restrict__ fut,
        const float* __restrict__ eps, const int* __restrict__ t_arr,
        const u16* __restrict__ uws, const float* __restrict__ b2,
        float* __restrict__ ws){
    __shared__ u16 sN[64 * PADN];
    __shared__ u16 sH[64 * PADH];
    __shared__ float sHs[512];
    __shared__ float sRed[8];
    int tid = threadIdx.x, bid = blockIdx.x;
    int* wsi = (int*)ws;
    int b, e, store;
    if(bid < 512){ b = bid; e = wsi[WS_SELECTED + b]; store = 0; }
    else { int r = bid - 512; e = r >> 2; b = r & 3; store = 1; }
    sHs[tid] = store ? ws[WS_HSTAT2 + (e*4 + b)*512 + tid] : ws[WS_HSTAT + b*512 + tid];
    int tv = t_arr[b];
    float ab = ws[WS_ALPHAS + tv];
    float sa = sqrtf(ab), sb = sqrtf(1.0f - ab);
    {
        int r = tid >> 3, c0 = (tid & 7) * 8;
        const f32x4* pf = (const f32x4*)&fut[((size_t)b*64 + r)*64 + c0];
        const f32x4* pe = (const f32x4*)&eps[((size_t)b*64 + r)*64 + c0];
        f32x4 f0 = pf[0], f1 = pf[1], e0 = pe[0], e1 = pe[1];
        u16x4 p0, p1;
        p0.x = f2bf(sa*f0.x + sb*e0.x); p0.y = f2bf(sa*f0.y + sb*e0.y);
        p0.z = f2bf(sa*f0.z + sb*e0.z); p0.w = f2bf(sa*f0.w + sb*e0.w);
        p1.x = f2bf(sa*f1.x + sb*e1.x); p1.y = f2bf(sa*f1.y + sb*e1.y);
        p1.z = f2bf(sa*f1.z + sb*e1.z); p1.w = f2bf(sa*f1.w + sb*e1.w);
        *(u16x4*)&sN[r*PADN + c0]     = p0;
        *(u16x4*)&sN[r*PADN + c0 + 4] = p1;
    }
    __syncthreads();
    int w = tid >> 6, l = tid & 63, lr = l & 15, lk = (l >> 4) * 8;
    const u16* w1T = uws + U_W1T;
    const u16* w2T = uws + U_W2T;
    f32x4 hacc[4][4];
    float hb[4];
    s16x8 bw[4][2];
    #pragma unroll
    for(int nt = 0; nt < 4; nt++){
        int col = w*64 + nt*16 + lr;
        hb[nt] = sHs[col];
        bw[nt][0] = *(const s16x8*)&w1T[((size_t)e*512 + col)*1088 + lk];
        bw[nt][1] = *(const s16x8*)&w1T[((size_t)e*512 + col)*1088 + 32 + lk];
    }
    #pragma unroll
    for(int mt = 0; mt < 4; mt++){
        s16x8 a0 = *(const s16x8*)&sN[(mt*16 + lr)*PADN + lk];
        s16x8 a1 = *(const s16x8*)&sN[(mt*16 + lr)*PADN + 32 + lk];
        #pragma unroll
        for(int nt = 0; nt < 4; nt++){
            f32x4 acc = {hb[nt], hb[nt], hb[nt], hb[nt]};
            mfma16(acc, a0, bw[nt][0]);
            mfma16(acc, a1, bw[nt][1]);
            hacc[mt][nt] = acc;
        }
    }
    #pragma unroll
    for(int mt = 0; mt < 4; mt++)
        #pragma unroll
        for(int nt = 0; nt < 4; nt++){
            int col = w*64 + nt*16 + lr;
            #pragma unroll
            for(int rg = 0; rg < 4; rg++){
                int row = mt*16 + (l >> 4)*4 + rg;
                sH[row*PADH + col] = f2bf(gelu_f(hacc[mt][nt][rg]));
            }
        }
    __syncthreads();
    int mtg = (w >> 2) << 1;
    int nt  = w & 3;
    f32x4 oacc[2];
    {
        float bz = b2[e*64 + nt*16 + lr];
        f32x4 z = {bz, bz, bz, bz}; oacc[0] = z; oacc[1] = z;
    }
    for(int ks = 0; ks < 16; ks++){
        s16x8 bb = *(const s16x8*)&w2T[((size_t)e*64 + nt*16 + lr)*512 + ks*32 + lk];
        #pragma unroll
        for(int i = 0; i < 2; i++){
            s16x8 a = *(const s16x8*)&sH[((mtg + i)*16 + lr)*PADH + ks*32 + lk];
            mfma16(oacc[i], a, bb);
        }
    }
    if(store){
        #pragma unroll
        for(int i = 0; i < 2; i++)
            #pragma unroll
            for(int rg = 0; rg < 4; rg++){
                int row = (mtg + i)*16 + (l >> 4)*4 + rg;
                int col = nt*16 + lr;
                ws[WS_OUTSUB + (e*4 + b)*4096 + row*64 + col] = oacc[i][rg];
            }
    } else {
        float ls = 0.f;
        #pragma unroll
        for(int i = 0; i < 2; i++)
            #pragma unroll
            for(int rg = 0; rg < 4; rg++){
                int row = (mtg + i)*16 + (l >> 4)*4 + rg;
                int col = nt*16 + lr;
                float d = oacc[i][rg] - eps[((size_t)b*64 + row)*64 + col];
                ls += d*d;
            }
        #pragma unroll
        for(int off = 32; off > 0; off >>= 1) ls += __shfl_down(ls, off);
        if(l == 0) sRed[w] = ls;
        __syncthreads();
        if(tid == 0){
            float s = 0.f;
            #pragma unroll
            for(int q = 0; q < 8; q++) s += sRed[q];
            const float pw[3] = {1.f, 5.f, 5.f};
            ws[WS_LOSSB + b] = (s * (1.0f/4096.0f)) * pw[e % 3];
        }
    }
}

// ---------------- k5a: chain (7) + smooth (6) partials ----------------
__global__ __launch_bounds__(256) void k5a_parts(float* __restrict__ ws){
    __shared__ float red[256];
    int bid = blockIdx.x, tid = threadIdx.x;
    float s = 0.f;
    if(bid < 7){
        const int pa[7] = {0,1,3,4,0,1,2};
        const int pb[7] = {1,2,4,5,3,4,5};
        const float* A  = &ws[WS_OUTSUB + pa[bid]*16384];
        const float* Bp = &ws[WS_OUTSUB + pb[bid]*16384];
        for(int i = tid; i < 4096; i += 256){
            f32x4 a = *(const f32x4*)&A[i*4];
            f32x4 c = *(const f32x4*)&Bp[i*4];
            f32x4 d = a - c;
            s += d.x*d.x + d.y*d.y + d.z*d.z + d.w*d.w;
        }
        s *= (1.0f/16384.0f);
    } else {
        int e = bid - 7;
        const float* O = &ws[WS_OUTSUB + e*16384];
        for(int i = tid; i < 4*63*16; i += 256){
            int sm = i / (63*16); int r = i % (63*16);
            int tf = r / 16; int f4 = (r % 16) * 4;
            f32x4 a = *(const f32x4*)&O[(sm*64 + tf + 1)*64 + f4];
            f32x4 c = *(const f32x4*)&O[(sm*64 + tf)*64 + f4];
            f32x4 d = a - c;
            s += d.x*d.x + d.y*d.y + d.z*d.z + d.w*d.w;
        }
        s *= (1.0f/16128.0f) * 0.5f;
    }
    red[tid] = s;
    __syncthreads();
    for(int st = 128; st > 0; st >>= 1){
        if(tid < st) red[tid] += red[tid + st];
        __syncthreads();
    }
    if(tid == 0) ws[WS_PARTS + bid] = red[0];
}

// ---------------- k5b: finalize ----------------
__global__ __launch_bounds__(512) void k5b_final(float* __restrict__ ws, float* __restrict__ out){
    __shared__ float rA[512], rB[512];
    int tid = threadIdx.x;
    int* wsi = (int*)ws;
    int sel = wsi[WS_SELECTED + tid];
    rA[tid] = ws[WS_LOSSB + tid];
    __syncthreads();
    for(int st = 256; st > 0; st >>= 1){ if(tid < st) rA[tid] += rA[tid + st]; __syncthreads(); }
    float total = 0.f;
    if(tid == 0){
        total = rA[0] * (1.0f/512.0f);
        float reg = 0.f;
        for(int p = 0; p < 13; p++) reg += ws[WS_PARTS + p];
        total += 0.01f * reg;
    }
    __syncthreads();
    float lb = 0.f;
    for(int e = 0; e < 6; e++){
        rA[tid] = (sel == e) ? 1.f : 0.f;
        rB[tid] = ws[WS_PROBS + tid*6 + e];
        __syncthreads();
        for(int st = 256; st > 0; st >>= 1){
            if(tid < st){ rA[tid] += rA[tid + st]; rB[tid] += rB[tid + st]; }
            __syncthreads();
        }
        if(tid == 0) lb += (rA[0] * (1.0f/512.f)) * (rB[0] * (1.0f/512.f));
        __syncthreads();
    }
    if(tid == 0) out[0] = total + 0.01f * 6.0f * lb;
}

extern "C" void kernel_launch(void* const* d_in, const int* in_sizes, int n_in,
                              void* d_out, int out_size, void* d_ws, size_t ws_size,
                              hipStream_t stream){
    const float* obs  = (const float*)d_in[0];
    const float* fut  = (const float*)d_in[1];
    const float* stat = (const float*)d_in[2];
    const float* eps  = (const float*)d_in[3];
    const int*   phase= (const int*)d_in[4];
    const int*   t    = (const int*)d_in[5];
    const float* Wenc = (const float*)d_in[6];
    const float* benc = (const float*)d_in[7];
    const float* Wstat= (const float*)d_in[8];
    const float* Wr   = (const float*)d_in[9];
    const float* br   = (const float*)d_in[10];
    const float* W1   = (const float*)d_in[11];
    const float* b1   = (const float*)d_in[12];
    const float* W2   = (const float*)d_in[13];
    const float* b2   = (const float*)d_in[14];
    float* ws  = (float*)d_ws;
    u16*   uws = (u16*)((char*)d_ws + WS_U16BYTE);
    float* out = (float*)d_out;

    k0T<<<3489, 256, 0, stream>>>(Wenc, W1, W2, uws, ws);
    k1_enc_mfma<<<1024, 512, 0, stream>>>(obs, stat, Wstat, benc, uws, ws);
    k2_router<<<512, 64, 0, stream>>>(Wr, br, phase, t, ws);
    k2b_group<<<1, 512, 0, stream>>>(ws);
    k3_hstat<<<112, 256, 0, stream>>>(uws, b1, ws);
    k4_ffn<<<536, 512, 0, stream>>>(fut, eps, t, uws, b2, ws);
    k5a_parts<<<13, 256, 0, stream>>>(ws);
    k5b_final<<<1, 512, 0, stream>>>(ws, out);
}

// Round 5
// 107.835 us; speedup vs baseline: 7.4101x; 1.0150x over previous
//
#include <hip/hip_runtime.h>

typedef float  f32x4 __attribute__((ext_vector_type(4)));
typedef short  s16x8 __attribute__((ext_vector_type(8)));
typedef unsigned short u16;
typedef u16    u16x4 __attribute__((ext_vector_type(4)));

#define TIMESTEPS 1000

// ---- ws float-offset map ----
#define WS_ALPHAS   0        // 1000 f
#define WS_FREQS    1024     // 256 f
#define WS_PROBS    1536     // 512*6 f
#define WS_SELECTED 4608     // 512 int
#define WS_LOSSB    5632     // 512 f
#define WS_META     6144     // int: [0]=nch, triples (e,start,len) stride 4
#define WS_ROWSRC   6400     // 640 int
#define WS_ROWDST   7040     // 640 int (float-offset into ws, -1 = skip)
#define WS_PARTS    7680     // 13 f
#define WS_GCTX     8192     // 512*512 f   (k1 partial q=0; dead after k2)
#define WS_XC       270336   // reused region: 512*1024 bf16 (u16) = 512 KB
#define WS_HSTAT    532480   // 512*512 f   (k1 partial q=1, then overwritten by k3)
#define WS_HSTAT2   794624   // 6*4*512 f
#define WS_OUTSUB   806912   // 6*4*64*64 f
#define WS_U16BYTE  3620864  // byte offset of u16 weight region (16B aligned)
#define WS_BIAS     2691072  // 512*512 f (after u16 region: byte 10764288)
// u16-offsets inside u16 region
#define U_WENCT     0        // 512*64
#define U_W1T       32768    // 6*512*1088
#define U_W2T       3375104  // 6*64*512

__device__ __forceinline__ u16 f2bf(float x){
    unsigned u = __builtin_bit_cast(unsigned, x);
    unsigned r = (u + 0x7FFFu + ((u >> 16) & 1u)) >> 16;
    return (u16)r;
}

__device__ __forceinline__ float gelu_f(float x){
    float x2 = x * x;
    float t  = x * fmaf(0.035677408136f, x2, 0.7978845608028654f);
    float ex = __builtin_amdgcn_exp2f(t * 2.885390081777927f);
    float r  = __builtin_amdgcn_rcpf(ex + 1.0f);
    return fmaf(-x, r, x);
}

__device__ __forceinline__ void mfma16(f32x4& c, s16x8 a, s16x8 b){
    asm volatile("v_mfma_f32_16x16x32_bf16 %0, %1, %2, %0" : "+v"(c) : "v"(a), "v"(b));
}

// ---------------- k0T: weight transposes + alphas/freqs + bias table ----------------
__global__ __launch_bounds__(256) void k0T(const float* __restrict__ Wenc,
                                           const float* __restrict__ W1,
                                           const float* __restrict__ W2,
                                           const float* __restrict__ stat,
                                           const float* __restrict__ Wstat,
                                           const float* __restrict__ benc,
                                           u16* __restrict__ uws,
                                           float* __restrict__ ws){
    __shared__ float sT[32][33];
    int bid = blockIdx.x, tid = threadIdx.x;
    const int t1 = 6*34*16, t2 = t1 + 6*16*2, t3 = t2 + 2*16;
    if(bid == t3){
        __shared__ float sp[256];
        for(int k = tid; k < 256; k += 256)
            ws[WS_FREQS + k] = expf(-logf(10000.0f) * (float)k / 256.0f);
        float p = 1.f;
        #pragma unroll
        for(int r = 0; r < 4; r++){
            int i = tid*4 + r;
            if(i < TIMESTEPS){
                float beta = 0.0001f + (0.02f - 0.0001f) * ((float)i / 999.0f);
                p *= (1.0f - beta);
            }
        }
        sp[tid] = p;
        __syncthreads();
        for(int st = 1; st < 256; st <<= 1){
            float v = (tid >= st) ? sp[tid - st] : 1.0f;
            __syncthreads();
            sp[tid] *= v;
            __syncthreads();
        }
        float run = (tid == 0) ? 1.0f : sp[tid - 1];
        for(int r = 0; r < 4; r++){
            int i = tid*4 + r;
            if(i < TIMESTEPS){
                float beta = 0.0001f + (0.02f - 0.0001f) * ((float)i / 999.0f);
                run *= (1.0f - beta);
                ws[WS_ALPHAS + i] = run;
            }
        }
        return;
    }
    if(bid > t3){
        // bias table: statB[b][j] = benc[j] + sum_s stat[b][s]*Wstat[s][j]
        __shared__ float sSt[8*32];
        int g = bid - t3 - 1;              // 0..63
        int b0 = g*8;
        sSt[tid & 255] = stat[b0*32 + (tid & 255)];
        __syncthreads();
        #pragma unroll
        for(int half = 0; half < 2; half++){
            int j = tid + half*256;
            float acc[8] = {0,0,0,0,0,0,0,0};
            for(int s = 0; s < 32; s++){
                float wv = Wstat[s*512 + j];
                #pragma unroll
                for(int bb = 0; bb < 8; bb++) acc[bb] += sSt[bb*32 + s] * wv;
            }
            float bz = benc[j];
            #pragma unroll
            for(int bb = 0; bb < 8; bb++)
                ws[WS_BIAS + (b0 + bb)*512 + j] = acc[bb] + bz;
        }
        return;
    }
    const float* src; u16* dst; int K, J, kt, jt;
    if(bid < t1){
        int e = bid / 544, r = bid % 544; kt = r / 16; jt = r % 16;
        src = W1 + (size_t)e*1088*512; dst = uws + U_W1T + (size_t)e*512*1088; K = 1088; J = 512;
    } else if(bid < t2){
        int r = bid - t1; int e = r / 32; r %= 32; kt = r / 2; jt = r % 2;
        src = W2 + (size_t)e*512*64; dst = uws + U_W2T + (size_t)e*64*512; K = 512; J = 64;
    } else {
        int r = bid - t2; kt = r / 16; jt = r % 16;
        src = Wenc; dst = uws + U_WENCT; K = 64; J = 512;
    }
    int ty = tid >> 5, tx = tid & 31;
    #pragma unroll
    for(int i = 0; i < 4; i++)
        sT[ty + i*8][tx] = src[(size_t)(kt*32 + ty + i*8)*J + jt*32 + tx];
    __syncthreads();
    #pragma unroll
    for(int i = 0; i < 4; i++)
        dst[(size_t)(jt*32 + ty + i*8)*K + kt*32 + tx] = f2bf(sT[tx][ty + i*8]);
}

// ---------------- k1: encoder via MFMA, 2-way row split ----------------
#define PADX 72
__global__ __launch_bounds__(512) void k1_enc_mfma(const float* __restrict__ obs,
        const u16* __restrict__ uws, float* __restrict__ ws){
    __shared__ u16  sX[128 * PADX];
    __shared__ float sBias[512];
    int bid = blockIdx.x, b = bid >> 1, q = bid & 1, tid = threadIdx.x;
    {
        int row = tid >> 2, c0 = (tid & 3) * 16;
        const f32x4* src = (const f32x4*)&obs[((size_t)(b*256 + q*128 + row))*64 + c0];
        u16* dst = &sX[row*PADX + c0];
        #pragma unroll
        for(int i = 0; i < 4; i++){
            f32x4 v = src[i];
            u16x4 pk; pk.x = f2bf(v.x); pk.y = f2bf(v.y); pk.z = f2bf(v.z); pk.w = f2bf(v.w);
            *(u16x4*)(dst + i*4) = pk;
        }
    }
    sBias[tid] = ws[WS_BIAS + b*512 + tid];
    __syncthreads();
    int w = tid >> 6, l = tid & 63, lr = l & 15, lk = (l >> 4) * 8;
    const u16* wencT = uws + U_WENCT;
    s16x8 bf[4][2];
    float bias[4];
    #pragma unroll
    for(int n = 0; n < 4; n++){
        int col = w*64 + n*16 + lr;
        bf[n][0] = *(const s16x8*)&wencT[col*64 + lk];
        bf[n][1] = *(const s16x8*)&wencT[col*64 + 32 + lk];
        bias[n]  = sBias[col];
    }
    float cac[4] = {0.f, 0.f, 0.f, 0.f};
    for(int mt = 0; mt < 8; mt++){
        s16x8 a0 = *(const s16x8*)&sX[(mt*16 + lr)*PADX + lk];
        s16x8 a1 = *(const s16x8*)&sX[(mt*16 + lr)*PADX + 32 + lk];
        #pragma unroll
        for(int n = 0; n < 4; n++){
            f32x4 acc = {bias[n], bias[n], bias[n], bias[n]};
            mfma16(acc, a0, bf[n][0]);
            mfma16(acc, a1, bf[n][1]);
            cac[n] += gelu_f(acc.x) + gelu_f(acc.y) + gelu_f(acc.z) + gelu_f(acc.w);
        }
    }
    #pragma unroll
    for(int n = 0; n < 4; n++){
        cac[n] += __shfl_xor(cac[n], 16);
        cac[n] += __shfl_xor(cac[n], 32);
    }
    float* pdst = q ? &ws[WS_HSTAT + b*512] : &ws[WS_GCTX + b*512];
    if(l < 16){
        #pragma unroll
        for(int n = 0; n < 4; n++)
            pdst[w*64 + n*16 + l] = cac[n];   // raw partial sum; k2 scales
    }
}

// ---------------- k2: combine partials + router + selection + XC(bf16) ----------------
__global__ __launch_bounds__(64) void k2_router(const float* __restrict__ Wr,
        const float* __restrict__ br, const int* __restrict__ phase,
        const int* __restrict__ t_arr, float* __restrict__ ws){
    int b = blockIdx.x, lane = threadIdx.x;
    float acc[6] = {0,0,0,0,0,0};
    int tv = t_arr[b];
    u16* XC = (u16*)(ws + WS_XC);
    for(int k = 0; k < 8; k++){
        int d = k*64 + lane;
        float gv = (ws[WS_GCTX + b*512 + d] + ws[WS_HSTAT + b*512 + d]) * (1.0f/256.0f);
        XC[b*1024 + d] = f2bf(gv);
        #pragma unroll
        for(int e = 0; e < 6; e++) acc[e] += gv * Wr[d*6 + e];
        float fr = ws[WS_FREQS + (d & 255)];
        float a = (float)tv * fr;
        XC[b*1024 + 512 + d] = f2bf((d < 256) ? sinf(a) : cosf(a));
    }
    #pragma unroll
    for(int off = 32; off > 0; off >>= 1)
        #pragma unroll
        for(int e = 0; e < 6; e++) acc[e] += __shfl_down(acc[e], off);
    if(lane == 0){
        float logit[6], mx = -1e30f;
        #pragma unroll
        for(int e = 0; e < 6; e++){ logit[e] = acc[e] + br[e]; mx = fmaxf(mx, logit[e]); }
        float s = 0.f, p[6];
        #pragma unroll
        for(int e = 0; e < 6; e++){ p[e] = expf(logit[e] - mx); s += p[e]; }
        float inv = 1.0f / s;
        #pragma unroll
        for(int e = 0; e < 6; e++) ws[WS_PROBS + b*6 + e] = p[e] * inv;
        int ph = phase[b];
        int sel = ph + ((logit[ph + 3] > logit[ph]) ? 3 : 0);
        ((int*)ws)[WS_SELECTED + b] = sel;
    }
}

// ---------------- k2b: build row list (loss rows + aux rows per expert section) ----------------
__global__ __launch_bounds__(512) void k2b_group(float* __restrict__ ws){
    __shared__ int sCnt[8][6];
    __shared__ int sBase[8][6];
    __shared__ int sSec[6], sTot[6];
    int tid = threadIdx.x, w = tid >> 6, l = tid & 63;
    int* wsi = (int*)ws;
    int sv = wsi[WS_SELECTED + tid];
    unsigned long long mym = 0;
    #pragma unroll
    for(int e = 0; e < 6; e++){
        unsigned long long m = __ballot(sv == e);
        if(l == 0) sCnt[w][e] = __popcll(m);
        if(sv == e) mym = m;
    }
    __syncthreads();
    if(tid == 0){
        int o = 0;
        for(int e = 0; e < 6; e++){
            sSec[e] = o;
            int t0 = 0;
            for(int ww = 0; ww < 8; ww++){ sBase[ww][e] = o; o += sCnt[ww][e]; t0 += sCnt[ww][e]; }
            sTot[e] = t0;
            o += 4;                       // reserve aux rows
        }
        int nch = 0;
        for(int e = 0; e < 6; e++){
            int len = sTot[e] + 4, st = sSec[e];
            for(int s = 0; s < len; s += 64){
                int cl = len - s; if(cl > 64) cl = 64;
                wsi[WS_META + 4 + nch*4 + 0] = e;
                wsi[WS_META + 4 + nch*4 + 1] = st + s;
                wsi[WS_META + 4 + nch*4 + 2] = cl;
                nch++;
            }
        }
        wsi[WS_META] = nch;
    }
    __syncthreads();
    int rank = __popcll(mym & ((1ull << l) - 1ull));
    int pos = sBase[w][sv] + rank;
    wsi[WS_ROWSRC + pos] = tid;
    wsi[WS_ROWDST + pos] = WS_HSTAT + tid*512;
    if(tid < 24){
        int e = tid >> 2, b = tid & 3;
        int pos2 = sSec[e] + sTot[e] + b;
        wsi[WS_ROWSRC + pos2] = b;
        wsi[WS_ROWDST + pos2] = WS_HSTAT2 + (e*4 + b)*512;
    }
}

// ---------------- k3: hstat GEMM, direct-global fragments, high parallelism ----------------
__global__ __launch_bounds__(256) void k3_hstat(const u16* __restrict__ uws,
        const float* __restrict__ b1, float* __restrict__ ws){
    __shared__ int sSrc[64], sDst[64];
    int bid = blockIdx.x, tid = threadIdx.x;
    int c = bid >> 3, jt = bid & 7;
    int* wsi = (int*)ws;
    if(c >= wsi[WS_META]) return;
    int e    = wsi[WS_META + 4 + c*4 + 0];
    int start= wsi[WS_META + 4 + c*4 + 1];
    int len  = wsi[WS_META + 4 + c*4 + 2];
    if(tid < 64){
        int ok = tid < len;
        sSrc[tid] = ok ? wsi[WS_ROWSRC + start + tid] : 0;
        sDst[tid] = ok ? wsi[WS_ROWDST + start + tid] : -1;
    }
    __syncthreads();
    int w = tid >> 6, l = tid & 63, lr = l & 15, lk = (l >> 4) * 8;
    int col = jt*64 + w*16 + lr;
    const u16* XC = (const u16*)(ws + WS_XC);
    const u16* rowA[4];
    #pragma unroll
    for(int mt = 0; mt < 4; mt++)
        rowA[mt] = XC + (size_t)sSrc[mt*16 + lr]*1024 + lk;
    const u16* bp = uws + U_W1T + ((size_t)e*512 + col)*1088 + 64 + lk;
    f32x4 acc[4];
    {
        float bv = b1[e*512 + col];
        f32x4 z = {bv, bv, bv, bv};
        #pragma unroll
        for(int mt = 0; mt < 4; mt++) acc[mt] = z;
    }
    #pragma unroll 4
    for(int ks = 0; ks < 32; ks++){
        s16x8 bb = *(const s16x8*)(bp + ks*32);
        s16x8 a0 = *(const s16x8*)(rowA[0] + ks*32);
        s16x8 a1 = *(const s16x8*)(rowA[1] + ks*32);
        s16x8 a2 = *(const s16x8*)(rowA[2] + ks*32);
        s16x8 a3 = *(const s16x8*)(rowA[3] + ks*32);
        mfma16(acc[0], a0, bb);
        mfma16(acc[1], a1, bb);
        mfma16(acc[2], a2, bb);
        mfma16(acc[3], a3, bb);
    }
    #pragma unroll
    for(int mt = 0; mt < 4; mt++){
        #pragma unroll
        for(int rg = 0; rg < 4; rg++){
            int r = mt*16 + (l >> 4)*4 + rg;
            int d = sDst[r];
            if(d >= 0) ws[d + col] = acc[mt][rg];
        }
    }
}

// ---------------- k4: per-sample FFN via MFMA, transposed h-head (b64 packed H writes) ----
#define PADN 72
#define PADH 520
__global__ __launch_bounds__(512) void k4_ffn(const float* __restrict__ fut,
        const float* __restrict__ eps, const int* __restrict__ t_arr,
        const u16* __restrict__ uws, const float* __restrict__ b2,
        float* __restrict__ ws){
    __shared__ u16 sN[64 * PADN];
    __shared__ u16 sH[64 * PADH];    // [tf][j] layout
    __shared__ float sHs[512];
    __shared__ float sRed[8];
    int tid = threadIdx.x, bid = blockIdx.x;
    int* wsi = (int*)ws;
    int b, e, store;
    if(bid < 512){ b = bid; e = wsi[WS_SELECTED + b]; store = 0; }
    else { int r = bid - 512; e = r >> 2; b = r & 3; store = 1; }
    sHs[tid] = store ? ws[WS_HSTAT2 + (e*4 + b)*512 + tid] : ws[WS_HSTAT + b*512 + tid];
    int tv = t_arr[b];
    float ab = ws[WS_ALPHAS + tv];
    float sa = sqrtf(ab), sb = sqrtf(1.0f - ab);
    {
        int r = tid >> 3, c0 = (tid & 7) * 8;
        const f32x4* pf = (const f32x4*)&fut[((size_t)b*64 + r)*64 + c0];
        const f32x4* pe = (const f32x4*)&eps[((size_t)b*64 + r)*64 + c0];
        f32x4 f0 = pf[0], f1 = pf[1], e0 = pe[0], e1 = pe[1];
        u16x4 p0, p1;
        p0.x = f2bf(sa*f0.x + sb*e0.x); p0.y = f2bf(sa*f0.y + sb*e0.y);
        p0.z = f2bf(sa*f0.z + sb*e0.z); p0.w = f2bf(sa*f0.w + sb*e0.w);
        p1.x = f2bf(sa*f1.x + sb*e1.x); p1.y = f2bf(sa*f1.y + sb*e1.y);
        p1.z = f2bf(sa*f1.z + sb*e1.z); p1.w = f2bf(sa*f1.w + sb*e1.w);
        *(u16x4*)&sN[r*PADN + c0]     = p0;
        *(u16x4*)&sN[r*PADN + c0 + 4] = p1;
    }
    __syncthreads();
    int w = tid >> 6, l = tid & 63, lr = l & 15, lk = (l >> 4) * 8;
    const u16* w1T = uws + U_W1T;
    const u16* w2T = uws + U_W2T;
    // h-head (swapped): hT[j][tf] = A(W1: row=j,k=d) x B(noisy: col=tf,k=d) + hstat[j]
    // wave w owns j in [w*64, w*64+64)
    s16x8 aw[4][2];
    #pragma unroll
    for(int mt = 0; mt < 4; mt++){
        int jrow = w*64 + mt*16 + lr;
        aw[mt][0] = *(const s16x8*)&w1T[((size_t)e*512 + jrow)*1088 + lk];
        aw[mt][1] = *(const s16x8*)&w1T[((size_t)e*512 + jrow)*1088 + 32 + lk];
    }
    #pragma unroll
    for(int nt = 0; nt < 4; nt++){
        s16x8 nb0 = *(const s16x8*)&sN[(nt*16 + lr)*PADN + lk];
        s16x8 nb1 = *(const s16x8*)&sN[(nt*16 + lr)*PADN + 32 + lk];
        #pragma unroll
        for(int mt = 0; mt < 4; mt++){
            int j0 = w*64 + mt*16 + (l >> 4)*4;
            f32x4 acc = *(const f32x4*)&sHs[j0];
            mfma16(acc, aw[mt][0], nb0);
            mfma16(acc, aw[mt][1], nb1);
            u16x4 pk;
            pk.x = f2bf(gelu_f(acc.x)); pk.y = f2bf(gelu_f(acc.y));
            pk.z = f2bf(gelu_f(acc.z)); pk.w = f2bf(gelu_f(acc.w));
            *(u16x4*)&sH[(nt*16 + lr)*PADH + j0] = pk;   // single b64 write
        }
    }
    __syncthreads();
    // out: out[64 tf][64 f], K=512. wave w: mt group = (w>>2)*2, nt = w&3
    int mtg = (w >> 2) << 1;
    int nt  = w & 3;
    f32x4 oacc[2];
    {
        float bz = b2[e*64 + nt*16 + lr];
        f32x4 z = {bz, bz, bz, bz}; oacc[0] = z; oacc[1] = z;
    }
    for(int ks = 0; ks < 16; ks++){
        s16x8 bb = *(const s16x8*)&w2T[((size_t)e*64 + nt*16 + lr)*512 + ks*32 + lk];
        #pragma unroll
        for(int i = 0; i < 2; i++){
            s16x8 a = *(const s16x8*)&sH[((mtg + i)*16 + lr)*PADH + ks*32 + lk];
            mfma16(oacc[i], a, bb);
        }
    }
    if(store){
        #pragma unroll
        for(int i = 0; i < 2; i++)
            #pragma unroll
            for(int rg = 0; rg < 4; rg++){
                int row = (mtg + i)*16 + (l >> 4)*4 + rg;
                int col = nt*16 + lr;
                ws[WS_OUTSUB + (e*4 + b)*4096 + row*64 + col] = oacc[i][rg];
            }
    } else {
        float ls = 0.f;
        #pragma unroll
        for(int i = 0; i < 2; i++)
            #pragma unroll
            for(int rg = 0; rg < 4; rg++){
                int row = (mtg + i)*16 + (l >> 4)*4 + rg;
                int col = nt*16 + lr;
                float d = oacc[i][rg] - eps[((size_t)b*64 + row)*64 + col];
                ls += d*d;
            }
        #pragma unroll
        for(int off = 32; off > 0; off >>= 1) ls += __shfl_down(ls, off);
        if(l == 0) sRed[w] = ls;
        __syncthreads();
        if(tid == 0){
            float s = 0.f;
            #pragma unroll
            for(int q = 0; q < 8; q++) s += sRed[q];
            const float pw[3] = {1.f, 5.f, 5.f};
            ws[WS_LOSSB + b] = (s * (1.0f/4096.0f)) * pw[e % 3];
        }
    }
}

// ---------------- k5a: chain (7) + smooth (6) partials ----------------
__global__ __launch_bounds__(256) void k5a_parts(float* __restrict__ ws){
    __shared__ float red[256];
    int bid = blockIdx.x, tid = threadIdx.x;
    float s = 0.f;
    if(bid < 7){
        const int pa[7] = {0,1,3,4,0,1,2};
        const int pb[7] = {1,2,4,5,3,4,5};
        const float* A  = &ws[WS_OUTSUB + pa[bid]*16384];
        const float* Bp = &ws[WS_OUTSUB + pb[bid]*16384];
        for(int i = tid; i < 4096; i += 256){
            f32x4 a = *(const f32x4*)&A[i*4];
            f32x4 c = *(const f32x4*)&Bp[i*4];
            f32x4 d = a - c;
            s += d.x*d.x + d.y*d.y + d.z*d.z + d.w*d.w;
        }
        s *= (1.0f/16384.0f);
    } else {
        int e = bid - 7;
        const float* O = &ws[WS_OUTSUB + e*16384];
        for(int i = tid; i < 4*63*16; i += 256){
            int sm = i / (63*16); int r = i % (63*16);
            int tf = r / 16; int f4 = (r % 16) * 4;
            f32x4 a = *(const f32x4*)&O[(sm*64 + tf + 1)*64 + f4];
            f32x4 c = *(const f32x4*)&O[(sm*64 + tf)*64 + f4];
            f32x4 d = a - c;
            s += d.x*d.x + d.y*d.y + d.z*d.z + d.w*d.w;
        }
        s *= (1.0f/16128.0f) * 0.5f;
    }
    red[tid] = s;
    __syncthreads();
    for(int st = 128; st > 0; st >>= 1){
        if(tid < st) red[tid] += red[tid + st];
        __syncthreads();
    }
    if(tid == 0) ws[WS_PARTS + bid] = red[0];
}

// ---------------- k5b: finalize (shfl-tree) ----------------
__global__ __launch_bounds__(512) void k5b_final(float* __restrict__ ws, float* __restrict__ out){
    __shared__ float sW[8];
    __shared__ float sF[8][6], sP[8][6];
    int tid = threadIdx.x, w = tid >> 6, l = tid & 63;
    int* wsi = (int*)ws;
    int sel = wsi[WS_SELECTED + tid];
    float lv = ws[WS_LOSSB + tid];
    float pv[6], cf[6];
    #pragma unroll
    for(int e = 0; e < 6; e++){
        pv[e] = ws[WS_PROBS + tid*6 + e];
        cf[e] = (sel == e) ? 1.f : 0.f;
    }
    #pragma unroll
    for(int off = 32; off > 0; off >>= 1){
        lv += __shfl_down(lv, off);
        #pragma unroll
        for(int e = 0; e < 6; e++){
            pv[e] += __shfl_down(pv[e], off);
            cf[e] += __shfl_down(cf[e], off);
        }
    }
    if(l == 0){
        sW[w] = lv;
        #pragma unroll
        for(int e = 0; e < 6; e++){ sF[w][e] = cf[e]; sP[w][e] = pv[e]; }
    }
    __syncthreads();
    if(tid == 0){
        float total = 0.f;
        for(int q = 0; q < 8; q++) total += sW[q];
        total *= (1.0f/512.0f);
        float reg = 0.f;
        for(int p = 0; p < 13; p++) reg += ws[WS_PARTS + p];
        total += 0.01f * reg;
        float lb = 0.f;
        for(int e = 0; e < 6; e++){
            float f = 0.f, pp = 0.f;
            for(int q = 0; q < 8; q++){ f += sF[q][e]; pp += sP[q][e]; }
            lb += (f * (1.0f/512.f)) * (pp * (1.0f/512.f));
        }
        out[0] = total + 0.01f * 6.0f * lb;
    }
}

extern "C" void kernel_launch(void* const* d_in, const int* in_sizes, int n_in,
                              void* d_out, int out_size, void* d_ws, size_t ws_size,
                              hipStream_t stream){
    const float* obs  = (const float*)d_in[0];
    const float* fut  = (const float*)d_in[1];
    const float* stat = (const float*)d_in[2];
    const float* eps  = (const float*)d_in[3];
    const int*   phase= (const int*)d_in[4];
    const int*   t    = (const int*)d_in[5];
    const float* Wenc = (const float*)d_in[6];
    const float* benc = (const float*)d_in[7];
    const float* Wstat= (const float*)d_in[8];
    const float* Wr   = (const float*)d_in[9];
    const float* br   = (const float*)d_in[10];
    const float* W1   = (const float*)d_in[11];
    const float* b1   = (const float*)d_in[12];
    const float* W2   = (const float*)d_in[13];
    const float* b2   = (const float*)d_in[14];
    float* ws  = (float*)d_ws;
    u16*   uws = (u16*)((char*)d_ws + WS_U16BYTE);
    float* out = (float*)d_out;

    k0T<<<3553, 256, 0, stream>>>(Wenc, W1, W2, stat, Wstat, benc, uws, ws);
    k1_enc_mfma<<<1024, 512, 0, stream>>>(obs, uws, ws);
    k2_router<<<512, 64, 0, stream>>>(Wr, br, phase, t, ws);
    k2b_group<<<1, 512, 0, stream>>>(ws);
    k3_hstat<<<112, 256, 0, stream>>>(uws, b1, ws);
    k4_ffn<<<536, 512, 0, stream>>>(fut, eps, t, uws, b2, ws);
    k5a_parts<<<13, 256, 0, stream>>>(ws);
    k5b_final<<<1, 512, 0, stream>>>(ws, out);
}

// Round 6
// 105.321 us; speedup vs baseline: 7.5871x; 1.0239x over previous
//
#include <hip/hip_runtime.h>

typedef float  f32x4 __attribute__((ext_vector_type(4)));
typedef short  s16x8 __attribute__((ext_vector_type(8)));
typedef unsigned short u16;
typedef u16    u16x4 __attribute__((ext_vector_type(4)));

#define TIMESTEPS 1000

// ---- ws float-offset map ----
#define WS_ALPHAS   0        // 1000 f
#define WS_FREQS    1024     // 256 f
#define WS_PROBS    1536     // 512*6 f
#define WS_SELECTED 4608     // 512 int
#define WS_LOSSB    5632     // 512 f
#define WS_META     6144     // int: [0]=nch, triples (e,start,len) stride 4
#define WS_ROWSRC   6400     // 640 int
#define WS_ROWDST   7040     // 640 int (float-offset into ws, -1 = skip)
#define WS_PARTS    7680     // 13 f
#define WS_XC       270336   // 512*1024 bf16 (u16) = 512 KB
#define WS_HSTAT    532480   // 512*512 f
#define WS_HSTAT2   794624   // 6*4*512 f
#define WS_OUTSUB   806912   // 6*4*64*64 f
#define WS_U16BYTE  3620864  // byte offset of u16 weight region (16B aligned)
#define WS_BIAS     2691072  // 512*512 f
// u16-offsets inside u16 region
#define U_WENCT     0        // 512*64
#define U_W1T       32768    // 6*512*1088
#define U_W2T       3375104  // 6*64*512

__device__ __forceinline__ u16 f2bf(float x){
    unsigned u = __builtin_bit_cast(unsigned, x);
    unsigned r = (u + 0x7FFFu + ((u >> 16) & 1u)) >> 16;
    return (u16)r;
}

__device__ __forceinline__ float gelu_f(float x){
    float x2 = x * x;
    float t  = x * fmaf(0.035677408136f, x2, 0.7978845608028654f);
    float ex = __builtin_amdgcn_exp2f(t * 2.885390081777927f);
    float r  = __builtin_amdgcn_rcpf(ex + 1.0f);
    return fmaf(-x, r, x);
}

__device__ __forceinline__ void mfma16(f32x4& c, s16x8 a, s16x8 b){
    asm volatile("v_mfma_f32_16x16x32_bf16 %0, %1, %2, %0" : "+v"(c) : "v"(a), "v"(b));
}

// ---------------- k0T: weight transposes + alphas/freqs + bias table ----------------
__global__ __launch_bounds__(256) void k0T(const float* __restrict__ Wenc,
                                           const float* __restrict__ W1,
                                           const float* __restrict__ W2,
                                           const float* __restrict__ stat,
                                           const float* __restrict__ Wstat,
                                           const float* __restrict__ benc,
                                           u16* __restrict__ uws,
                                           float* __restrict__ ws){
    __shared__ float sT[32][33];
    int bid = blockIdx.x, tid = threadIdx.x;
    const int t1 = 6*34*16, t2 = t1 + 6*16*2, t3 = t2 + 2*16;
    if(bid == t3){
        __shared__ float sp[256];
        for(int k = tid; k < 256; k += 256)
            ws[WS_FREQS + k] = expf(-logf(10000.0f) * (float)k / 256.0f);
        float p = 1.f;
        #pragma unroll
        for(int r = 0; r < 4; r++){
            int i = tid*4 + r;
            if(i < TIMESTEPS){
                float beta = 0.0001f + (0.02f - 0.0001f) * ((float)i / 999.0f);
                p *= (1.0f - beta);
            }
        }
        sp[tid] = p;
        __syncthreads();
        for(int st = 1; st < 256; st <<= 1){
            float v = (tid >= st) ? sp[tid - st] : 1.0f;
            __syncthreads();
            sp[tid] *= v;
            __syncthreads();
        }
        float run = (tid == 0) ? 1.0f : sp[tid - 1];
        for(int r = 0; r < 4; r++){
            int i = tid*4 + r;
            if(i < TIMESTEPS){
                float beta = 0.0001f + (0.02f - 0.0001f) * ((float)i / 999.0f);
                run *= (1.0f - beta);
                ws[WS_ALPHAS + i] = run;
            }
        }
        return;
    }
    if(bid > t3){
        __shared__ float sSt[8*32];
        int g = bid - t3 - 1;              // 0..63
        int b0 = g*8;
        sSt[tid & 255] = stat[b0*32 + (tid & 255)];
        __syncthreads();
        #pragma unroll
        for(int half = 0; half < 2; half++){
            int j = tid + half*256;
            float acc[8] = {0,0,0,0,0,0,0,0};
            for(int s = 0; s < 32; s++){
                float wv = Wstat[s*512 + j];
                #pragma unroll
                for(int bb = 0; bb < 8; bb++) acc[bb] += sSt[bb*32 + s] * wv;
            }
            float bz = benc[j];
            #pragma unroll
            for(int bb = 0; bb < 8; bb++)
                ws[WS_BIAS + (b0 + bb)*512 + j] = acc[bb] + bz;
        }
        return;
    }
    const float* src; u16* dst; int K, J, kt, jt;
    if(bid < t1){
        int e = bid / 544, r = bid % 544; kt = r / 16; jt = r % 16;
        src = W1 + (size_t)e*1088*512; dst = uws + U_W1T + (size_t)e*512*1088; K = 1088; J = 512;
    } else if(bid < t2){
        int r = bid - t1; int e = r / 32; r %= 32; kt = r / 2; jt = r % 2;
        src = W2 + (size_t)e*512*64; dst = uws + U_W2T + (size_t)e*64*512; K = 512; J = 64;
    } else {
        int r = bid - t2; kt = r / 16; jt = r % 16;
        src = Wenc; dst = uws + U_WENCT; K = 64; J = 512;
    }
    int ty = tid >> 5, tx = tid & 31;
    #pragma unroll
    for(int i = 0; i < 4; i++)
        sT[ty + i*8][tx] = src[(size_t)(kt*32 + ty + i*8)*J + jt*32 + tx];
    __syncthreads();
    #pragma unroll
    for(int i = 0; i < 4; i++)
        dst[(size_t)(jt*32 + ty + i*8)*K + kt*32 + tx] = f2bf(sT[tx][ty + i*8]);
}

// ---------------- k1: encoder + router + selection + XC, fully fused (1 block / sample) ----
#define PADX 72
__global__ __launch_bounds__(512) void k1_enc(const float* __restrict__ obs,
        const u16* __restrict__ uws, const float* __restrict__ Wr,
        const float* __restrict__ br, const int* __restrict__ phase,
        const int* __restrict__ t_arr, float* __restrict__ ws){
    __shared__ u16  sX[256 * PADX];    // 36.9 KB
    __shared__ float sBias[512];
    __shared__ float sG[512];
    __shared__ float sRed[8][6];
    int b = blockIdx.x, tid = threadIdx.x;
    {   // stage obs 256x64 -> bf16
        int row = tid >> 1, c0 = (tid & 1) * 32;
        const f32x4* src = (const f32x4*)&obs[((size_t)b*256 + row)*64 + c0];
        u16* dst = &sX[row*PADX + c0];
        #pragma unroll
        for(int i = 0; i < 8; i++){
            f32x4 v = src[i];
            u16x4 pk; pk.x = f2bf(v.x); pk.y = f2bf(v.y); pk.z = f2bf(v.z); pk.w = f2bf(v.w);
            *(u16x4*)(dst + i*4) = pk;
        }
    }
    sBias[tid] = ws[WS_BIAS + b*512 + tid];
    __syncthreads();
    int w = tid >> 6, l = tid & 63, lr = l & 15, lk = (l >> 4) * 8;
    const u16* wencT = uws + U_WENCT;
    s16x8 bf[4][2];
    float bias[4];
    #pragma unroll
    for(int n = 0; n < 4; n++){
        int col = w*64 + n*16 + lr;
        bf[n][0] = *(const s16x8*)&wencT[col*64 + lk];
        bf[n][1] = *(const s16x8*)&wencT[col*64 + 32 + lk];
        bias[n]  = sBias[col];
    }
    float cac[4] = {0.f, 0.f, 0.f, 0.f};
    for(int mt = 0; mt < 16; mt++){
        s16x8 a0 = *(const s16x8*)&sX[(mt*16 + lr)*PADX + lk];
        s16x8 a1 = *(const s16x8*)&sX[(mt*16 + lr)*PADX + 32 + lk];
        #pragma unroll
        for(int n = 0; n < 4; n++){
            f32x4 acc = {bias[n], bias[n], bias[n], bias[n]};
            mfma16(acc, a0, bf[n][0]);
            mfma16(acc, a1, bf[n][1]);
            cac[n] += gelu_f(acc.x) + gelu_f(acc.y) + gelu_f(acc.z) + gelu_f(acc.w);
        }
    }
    #pragma unroll
    for(int n = 0; n < 4; n++){
        cac[n] += __shfl_xor(cac[n], 16);
        cac[n] += __shfl_xor(cac[n], 32);
    }
    if(l < 16){
        #pragma unroll
        for(int n = 0; n < 4; n++)
            sG[w*64 + n*16 + l] = cac[n] * (1.0f/256.0f);
    }
    __syncthreads();
    // gctx ready in sG; write XC, t_emb, router partials
    float gv = sG[tid];
    u16* XC = (u16*)(ws + WS_XC);
    XC[b*1024 + tid] = f2bf(gv);
    int tv = t_arr[b];
    {
        float fr = ws[WS_FREQS + (tid & 255)];
        float ang = (float)tv * fr;
        XC[b*1024 + 512 + tid] = f2bf((tid < 256) ? sinf(ang) : cosf(ang));
    }
    float p6[6];
    #pragma unroll
    for(int e = 0; e < 6; e++) p6[e] = gv * Wr[tid*6 + e];
    #pragma unroll
    for(int off = 32; off > 0; off >>= 1)
        #pragma unroll
        for(int e = 0; e < 6; e++) p6[e] += __shfl_down(p6[e], off);
    if(l == 0)
        #pragma unroll
        for(int e = 0; e < 6; e++) sRed[w][e] = p6[e];
    __syncthreads();
    if(tid == 0){
        float logit[6], mx = -1e30f;
        #pragma unroll
        for(int e = 0; e < 6; e++){
            float s = 0.f;
            #pragma unroll
            for(int q = 0; q < 8; q++) s += sRed[q][e];
            logit[e] = s + br[e];
            mx = fmaxf(mx, logit[e]);
        }
        float s = 0.f, p[6];
        #pragma unroll
        for(int e = 0; e < 6; e++){ p[e] = expf(logit[e] - mx); s += p[e]; }
        float inv = 1.0f / s;
        #pragma unroll
        for(int e = 0; e < 6; e++) ws[WS_PROBS + b*6 + e] = p[e] * inv;
        int ph = phase[b];
        int sel = ph + ((logit[ph + 3] > logit[ph]) ? 3 : 0);
        ((int*)ws)[WS_SELECTED + b] = sel;
    }
}

// ---------------- k2b: build row list (loss rows + aux rows per expert section) ----------------
__global__ __launch_bounds__(512) void k2b_group(float* __restrict__ ws){
    __shared__ int sCnt[8][6];
    __shared__ int sBase[8][6];
    __shared__ int sSec[6], sTot[6];
    int tid = threadIdx.x, w = tid >> 6, l = tid & 63;
    int* wsi = (int*)ws;
    int sv = wsi[WS_SELECTED + tid];
    unsigned long long mym = 0;
    #pragma unroll
    for(int e = 0; e < 6; e++){
        unsigned long long m = __ballot(sv == e);
        if(l == 0) sCnt[w][e] = __popcll(m);
        if(sv == e) mym = m;
    }
    __syncthreads();
    if(tid == 0){
        int o = 0;
        for(int e = 0; e < 6; e++){
            sSec[e] = o;
            int t0 = 0;
            for(int ww = 0; ww < 8; ww++){ sBase[ww][e] = o; o += sCnt[ww][e]; t0 += sCnt[ww][e]; }
            sTot[e] = t0;
            o += 4;                       // reserve aux rows
        }
        int nch = 0;
        for(int e = 0; e < 6; e++){
            int len = sTot[e] + 4, st = sSec[e];
            for(int s = 0; s < len; s += 64){
                int cl = len - s; if(cl > 64) cl = 64;
                wsi[WS_META + 4 + nch*4 + 0] = e;
                wsi[WS_META + 4 + nch*4 + 1] = st + s;
                wsi[WS_META + 4 + nch*4 + 2] = cl;
                nch++;
            }
        }
        wsi[WS_META] = nch;
    }
    __syncthreads();
    int rank = __popcll(mym & ((1ull << l) - 1ull));
    int pos = sBase[w][sv] + rank;
    wsi[WS_ROWSRC + pos] = tid;
    wsi[WS_ROWDST + pos] = WS_HSTAT + tid*512;
    if(tid < 24){
        int e = tid >> 2, b = tid & 3;
        int pos2 = sSec[e] + sTot[e] + b;
        wsi[WS_ROWSRC + pos2] = b;
        wsi[WS_ROWDST + pos2] = WS_HSTAT2 + (e*4 + b)*512;
    }
}

// ---------------- k3: hstat GEMM, direct-global fragments, high parallelism ----------------
__global__ __launch_bounds__(256) void k3_hstat(const u16* __restrict__ uws,
        const float* __restrict__ b1, float* __restrict__ ws){
    __shared__ int sSrc[64], sDst[64];
    int bid = blockIdx.x, tid = threadIdx.x;
    int c = bid >> 3, jt = bid & 7;
    int* wsi = (int*)ws;
    if(c >= wsi[WS_META]) return;
    int e    = wsi[WS_META + 4 + c*4 + 0];
    int start= wsi[WS_META + 4 + c*4 + 1];
    int len  = wsi[WS_META + 4 + c*4 + 2];
    if(tid < 64){
        int ok = tid < len;
        sSrc[tid] = ok ? wsi[WS_ROWSRC + start + tid] : 0;
        sDst[tid] = ok ? wsi[WS_ROWDST + start + tid] : -1;
    }
    __syncthreads();
    int w = tid >> 6, l = tid & 63, lr = l & 15, lk = (l >> 4) * 8;
    int col = jt*64 + w*16 + lr;
    const u16* XC = (const u16*)(ws + WS_XC);
    const u16* rowA[4];
    #pragma unroll
    for(int mt = 0; mt < 4; mt++)
        rowA[mt] = XC + (size_t)sSrc[mt*16 + lr]*1024 + lk;
    const u16* bp = uws + U_W1T + ((size_t)e*512 + col)*1088 + 64 + lk;
    f32x4 acc[4];
    {
        float bv = b1[e*512 + col];
        f32x4 z = {bv, bv, bv, bv};
        #pragma unroll
        for(int mt = 0; mt < 4; mt++) acc[mt] = z;
    }
    #pragma unroll 4
    for(int ks = 0; ks < 32; ks++){
        s16x8 bb = *(const s16x8*)(bp + ks*32);
        s16x8 a0 = *(const s16x8*)(rowA[0] + ks*32);
        s16x8 a1 = *(const s16x8*)(rowA[1] + ks*32);
        s16x8 a2 = *(const s16x8*)(rowA[2] + ks*32);
        s16x8 a3 = *(const s16x8*)(rowA[3] + ks*32);
        mfma16(acc[0], a0, bb);
        mfma16(acc[1], a1, bb);
        mfma16(acc[2], a2, bb);
        mfma16(acc[3], a3, bb);
    }
    #pragma unroll
    for(int mt = 0; mt < 4; mt++){
        #pragma unroll
        for(int rg = 0; rg < 4; rg++){
            int r = mt*16 + (l >> 4)*4 + rg;
            int d = sDst[r];
            if(d >= 0) ws[d + col] = acc[mt][rg];
        }
    }
}

// ---------------- k4: per-sample FFN via MFMA, transposed h-head ----------------
#define PADN 72
#define PADH 520
__global__ __launch_bounds__(512) void k4_ffn(const float* __restrict__ fut,
        const float* __restrict__ eps, const int* __restrict__ t_arr,
        const u16* __restrict__ uws, const float* __restrict__ b2,
        float* __restrict__ ws){
    __shared__ u16 sN[64 * PADN];
    __shared__ u16 sH[64 * PADH];    // [tf][j] layout
    __shared__ float sHs[512];
    __shared__ float sRed[8];
    int tid = threadIdx.x, bid = blockIdx.x;
    int* wsi = (int*)ws;
    int b, e, store;
    if(bid < 512){ b = bid; e = wsi[WS_SELECTED + b]; store = 0; }
    else { int r = bid - 512; e = r >> 2; b = r & 3; store = 1; }
    sHs[tid] = store ? ws[WS_HSTAT2 + (e*4 + b)*512 + tid] : ws[WS_HSTAT + b*512 + tid];
    int tv = t_arr[b];
    float ab = ws[WS_ALPHAS + tv];
    float sa = sqrtf(ab), sb = sqrtf(1.0f - ab);
    {
        int r = tid >> 3, c0 = (tid & 7) * 8;
        const f32x4* pf = (const f32x4*)&fut[((size_t)b*64 + r)*64 + c0];
        const f32x4* pe = (const f32x4*)&eps[((size_t)b*64 + r)*64 + c0];
        f32x4 f0 = pf[0], f1 = pf[1], e0 = pe[0], e1 = pe[1];
        u16x4 p0, p1;
        p0.x = f2bf(sa*f0.x + sb*e0.x); p0.y = f2bf(sa*f0.y + sb*e0.y);
        p0.z = f2bf(sa*f0.z + sb*e0.z); p0.w = f2bf(sa*f0.w + sb*e0.w);
        p1.x = f2bf(sa*f1.x + sb*e1.x); p1.y = f2bf(sa*f1.y + sb*e1.y);
        p1.z = f2bf(sa*f1.z + sb*e1.z); p1.w = f2bf(sa*f1.w + sb*e1.w);
        *(u16x4*)&sN[r*PADN + c0]     = p0;
        *(u16x4*)&sN[r*PADN + c0 + 4] = p1;
    }
    __syncthreads();
    int w = tid >> 6, l = tid & 63, lr = l & 15, lk = (l >> 4) * 8;
    const u16* w1T = uws + U_W1T;
    const u16* w2T = uws + U_W2T;
    s16x8 aw[4][2];
    #pragma unroll
    for(int mt = 0; mt < 4; mt++){
        int jrow = w*64 + mt*16 + lr;
        aw[mt][0] = *(const s16x8*)&w1T[((size_t)e*512 + jrow)*1088 + lk];
        aw[mt][1] = *(const s16x8*)&w1T[((size_t)e*512 + jrow)*1088 + 32 + lk];
    }
    #pragma unroll
    for(int nt = 0; nt < 4; nt++){
        s16x8 nb0 = *(const s16x8*)&sN[(nt*16 + lr)*PADN + lk];
        s16x8 nb1 = *(const s16x8*)&sN[(nt*16 + lr)*PADN + 32 + lk];
        #pragma unroll
        for(int mt = 0; mt < 4; mt++){
            int j0 = w*64 + mt*16 + (l >> 4)*4;
            f32x4 acc = *(const f32x4*)&sHs[j0];
            mfma16(acc, aw[mt][0], nb0);
            mfma16(acc, aw[mt][1], nb1);
            u16x4 pk;
            pk.x = f2bf(gelu_f(acc.x)); pk.y = f2bf(gelu_f(acc.y));
            pk.z = f2bf(gelu_f(acc.z)); pk.w = f2bf(gelu_f(acc.w));
            *(u16x4*)&sH[(nt*16 + lr)*PADH + j0] = pk;   // single b64 write
        }
    }
    __syncthreads();
    int mtg = (w >> 2) << 1;
    int nt  = w & 3;
    f32x4 oacc[2];
    {
        float bz = b2[e*64 + nt*16 + lr];
        f32x4 z = {bz, bz, bz, bz}; oacc[0] = z; oacc[1] = z;
    }
    for(int ks = 0; ks < 16; ks++){
        s16x8 bb = *(const s16x8*)&w2T[((size_t)e*64 + nt*16 + lr)*512 + ks*32 + lk];
        #pragma unroll
        for(int i = 0; i < 2; i++){
            s16x8 a = *(const s16x8*)&sH[((mtg + i)*16 + lr)*PADH + ks*32 + lk];
            mfma16(oacc[i], a, bb);
        }
    }
    if(store){
        #pragma unroll
        for(int i = 0; i < 2; i++)
            #pragma unroll
            for(int rg = 0; rg < 4; rg++){
                int row = (mtg + i)*16 + (l >> 4)*4 + rg;
                int col = nt*16 + lr;
                ws[WS_OUTSUB + (e*4 + b)*4096 + row*64 + col] = oacc[i][rg];
            }
    } else {
        float ls = 0.f;
        #pragma unroll
        for(int i = 0; i < 2; i++)
            #pragma unroll
            for(int rg = 0; rg < 4; rg++){
                int row = (mtg + i)*16 + (l >> 4)*4 + rg;
                int col = nt*16 + lr;
                float d = oacc[i][rg] - eps[((size_t)b*64 + row)*64 + col];
                ls += d*d;
            }
        #pragma unroll
        for(int off = 32; off > 0; off >>= 1) ls += __shfl_down(ls, off);
        if(l == 0) sRed[w] = ls;
        __syncthreads();
        if(tid == 0){
            float s = 0.f;
            #pragma unroll
            for(int q = 0; q < 8; q++) s += sRed[q];
            const float pw[3] = {1.f, 5.f, 5.f};
            ws[WS_LOSSB + b] = (s * (1.0f/4096.0f)) * pw[e % 3];
        }
    }
}

// ---------------- k5a: chain (7) + smooth (6) partials ----------------
__global__ __launch_bounds__(256) void k5a_parts(float* __restrict__ ws){
    __shared__ float red[256];
    int bid = blockIdx.x, tid = threadIdx.x;
    float s = 0.f;
    if(bid < 7){
        const int pa[7] = {0,1,3,4,0,1,2};
        const int pb[7] = {1,2,4,5,3,4,5};
        const float* A  = &ws[WS_OUTSUB + pa[bid]*16384];
        const float* Bp = &ws[WS_OUTSUB + pb[bid]*16384];
        for(int i = tid; i < 4096; i += 256){
            f32x4 a = *(const f32x4*)&A[i*4];
            f32x4 c = *(const f32x4*)&Bp[i*4];
            f32x4 d = a - c;
            s += d.x*d.x + d.y*d.y + d.z*d.z + d.w*d.w;
        }
        s *= (1.0f/16384.0f);
    } else {
        int e = bid - 7;
        const float* O = &ws[WS_OUTSUB + e*16384];
        for(int i = tid; i < 4*63*16; i += 256){
            int sm = i / (63*16); int r = i % (63*16);
            int tf = r / 16; int f4 = (r % 16) * 4;
            f32x4 a = *(const f32x4*)&O[(sm*64 + tf + 1)*64 + f4];
            f32x4 c = *(const f32x4*)&O[(sm*64 + tf)*64 + f4];
            f32x4 d = a - c;
            s += d.x*d.x + d.y*d.y + d.z*d.z + d.w*d.w;
        }
        s *= (1.0f/16128.0f) * 0.5f;
    }
    red[tid] = s;
    __syncthreads();
    for(int st = 128; st > 0; st >>= 1){
        if(tid < st) red[tid] += red[tid + st];
        __syncthreads();
    }
    if(tid == 0) ws[WS_PARTS + bid] = red[0];
}

// ---------------- k5b: finalize (shfl-tree) ----------------
__global__ __launch_bounds__(512) void k5b_final(float* __restrict__ ws, float* __restrict__ out){
    __shared__ float sW[8];
    __shared__ float sF[8][6], sP[8][6];
    int tid = threadIdx.x, w = tid >> 6, l = tid & 63;
    int* wsi = (int*)ws;
    int sel = wsi[WS_SELECTED + tid];
    float lv = ws[WS_LOSSB + tid];
    float pv[6], cf[6];
    #pragma unroll
    for(int e = 0; e < 6; e++){
        pv[e] = ws[WS_PROBS + tid*6 + e];
        cf[e] = (sel == e) ? 1.f : 0.f;
    }
    #pragma unroll
    for(int off = 32; off > 0; off >>= 1){
        lv += __shfl_down(lv, off);
        #pragma unroll
        for(int e = 0; e < 6; e++){
            pv[e] += __shfl_down(pv[e], off);
            cf[e] += __shfl_down(cf[e], off);
        }
    }
    if(l == 0){
        sW[w] = lv;
        #pragma unroll
        for(int e = 0; e < 6; e++){ sF[w][e] = cf[e]; sP[w][e] = pv[e]; }
    }
    __syncthreads();
    if(tid == 0){
        float total = 0.f;
        for(int q = 0; q < 8; q++) total += sW[q];
        total *= (1.0f/512.0f);
        float reg = 0.f;
        for(int p = 0; p < 13; p++) reg += ws[WS_PARTS + p];
        total += 0.01f * reg;
        float lb = 0.f;
        for(int e = 0; e < 6; e++){
            float f = 0.f, pp = 0.f;
            for(int q = 0; q < 8; q++){ f += sF[q][e]; pp += sP[q][e]; }
            lb += (f * (1.0f/512.f)) * (pp * (1.0f/512.f));
        }
        out[0] = total + 0.01f * 6.0f * lb;
    }
}

extern "C" void kernel_launch(void* const* d_in, const int* in_sizes, int n_in,
                              void* d_out, int out_size, void* d_ws, size_t ws_size,
                              hipStream_t stream){
    const float* obs  = (const float*)d_in[0];
    const float* fut  = (const float*)d_in[1];
    const float* stat = (const float*)d_in[2];
    const float* eps  = (const float*)d_in[3];
    const int*   phase= (const int*)d_in[4];
    const int*   t    = (const int*)d_in[5];
    const float* Wenc = (const float*)d_in[6];
    const float* benc = (const float*)d_in[7];
    const float* Wstat= (const float*)d_in[8];
    const float* Wr   = (const float*)d_in[9];
    const float* br   = (const float*)d_in[10];
    const float* W1   = (const float*)d_in[11];
    const float* b1   = (const float*)d_in[12];
    const float* W2   = (const float*)d_in[13];
    const float* b2   = (const float*)d_in[14];
    float* ws  = (float*)d_ws;
    u16*   uws = (u16*)((char*)d_ws + WS_U16BYTE);
    float* out = (float*)d_out;

    k0T<<<3553, 256, 0, stream>>>(Wenc, W1, W2, stat, Wstat, benc, uws, ws);
    k1_enc<<<512, 512, 0, stream>>>(obs, uws, Wr, br, phase, t, ws);
    k2b_group<<<1, 512, 0, stream>>>(ws);
    k3_hstat<<<112, 256, 0, stream>>>(uws, b1, ws);
    k4_ffn<<<536, 512, 0, stream>>>(fut, eps, t, uws, b2, ws);
    k5a_parts<<<13, 256, 0, stream>>>(ws);
    k5b_final<<<1, 512, 0, stream>>>(ws, out);
}

// Round 7
// 104.130 us; speedup vs baseline: 7.6738x; 1.0114x over previous
//
#include <hip/hip_runtime.h>

typedef float  f32x4 __attribute__((ext_vector_type(4)));
typedef short  s16x8 __attribute__((ext_vector_type(8)));
typedef unsigned short u16;
typedef u16    u16x4 __attribute__((ext_vector_type(4)));

#define TIMESTEPS 1000

// ---- ws float-offset map ----
#define WS_ALPHAS   0        // 1000 f
#define WS_FREQS    1024     // 256 f
#define WS_PROBS    1536     // 512*6 f
#define WS_SELECTED 4608     // 512 int
#define WS_LOSSB    5632     // 512 f
#define WS_PARTS    7680     // 13 f
#define WS_FLAG     7700     // 1 int (k5 join counter; reset by k3 block 0)
#define WS_XC       270336   // 512*1024 bf16 (u16) = 512 KB
#define WS_HSTAT    532480   // 512*512 f
#define WS_HSTAT2   794624   // 6*4*512 f
#define WS_OUTSUB   806912   // 6*4*64*64 f
#define WS_U16BYTE  3620864  // byte offset of u16 weight region (16B aligned)
#define WS_BIAS     2691072  // 512*512 f
// u16-offsets inside u16 region
#define U_WENCT     0        // 512*64
#define U_W1T       32768    // 6*512*1088
#define U_W2T       3375104  // 6*64*512

__device__ __forceinline__ u16 f2bf(float x){
    unsigned u = __builtin_bit_cast(unsigned, x);
    unsigned r = (u + 0x7FFFu + ((u >> 16) & 1u)) >> 16;
    return (u16)r;
}

__device__ __forceinline__ float gelu_f(float x){
    float x2 = x * x;
    float t  = x * fmaf(0.035677408136f, x2, 0.7978845608028654f);
    float ex = __builtin_amdgcn_exp2f(t * 2.885390081777927f);
    float r  = __builtin_amdgcn_rcpf(ex + 1.0f);
    return fmaf(-x, r, x);
}

__device__ __forceinline__ void mfma16(f32x4& c, s16x8 a, s16x8 b){
    asm volatile("v_mfma_f32_16x16x32_bf16 %0, %1, %2, %0" : "+v"(c) : "v"(a), "v"(b));
}

// ---------------- k0T: weight transposes + alphas/freqs + bias table ----------------
__global__ __launch_bounds__(256) void k0T(const float* __restrict__ Wenc,
                                           const float* __restrict__ W1,
                                           const float* __restrict__ W2,
                                           const float* __restrict__ stat,
                                           const float* __restrict__ Wstat,
                                           const float* __restrict__ benc,
                                           u16* __restrict__ uws,
                                           float* __restrict__ ws){
    __shared__ float sT[32][33];
    int bid = blockIdx.x, tid = threadIdx.x;
    const int t1 = 6*34*16, t2 = t1 + 6*16*2, t3 = t2 + 2*16;
    if(bid == t3){
        __shared__ float sp[256];
        for(int k = tid; k < 256; k += 256)
            ws[WS_FREQS + k] = expf(-logf(10000.0f) * (float)k / 256.0f);
        float p = 1.f;
        #pragma unroll
        for(int r = 0; r < 4; r++){
            int i = tid*4 + r;
            if(i < TIMESTEPS){
                float beta = 0.0001f + (0.02f - 0.0001f) * ((float)i / 999.0f);
                p *= (1.0f - beta);
            }
        }
        sp[tid] = p;
        __syncthreads();
        for(int st = 1; st < 256; st <<= 1){
            float v = (tid >= st) ? sp[tid - st] : 1.0f;
            __syncthreads();
            sp[tid] *= v;
            __syncthreads();
        }
        float run = (tid == 0) ? 1.0f : sp[tid - 1];
        for(int r = 0; r < 4; r++){
            int i = tid*4 + r;
            if(i < TIMESTEPS){
                float beta = 0.0001f + (0.02f - 0.0001f) * ((float)i / 999.0f);
                run *= (1.0f - beta);
                ws[WS_ALPHAS + i] = run;
            }
        }
        return;
    }
    if(bid > t3){
        __shared__ float sSt[8*32];
        int g = bid - t3 - 1;              // 0..63
        int b0 = g*8;
        sSt[tid & 255] = stat[b0*32 + (tid & 255)];
        __syncthreads();
        #pragma unroll
        for(int half = 0; half < 2; half++){
            int j = tid + half*256;
            float acc[8] = {0,0,0,0,0,0,0,0};
            for(int s = 0; s < 32; s++){
                float wv = Wstat[s*512 + j];
                #pragma unroll
                for(int bb = 0; bb < 8; bb++) acc[bb] += sSt[bb*32 + s] * wv;
            }
            float bz = benc[j];
            #pragma unroll
            for(int bb = 0; bb < 8; bb++)
                ws[WS_BIAS + (b0 + bb)*512 + j] = acc[bb] + bz;
        }
        return;
    }
    const float* src; u16* dst; int K, J, kt, jt;
    if(bid < t1){
        int e = bid / 544, r = bid % 544; kt = r / 16; jt = r % 16;
        src = W1 + (size_t)e*1088*512; dst = uws + U_W1T + (size_t)e*512*1088; K = 1088; J = 512;
    } else if(bid < t2){
        int r = bid - t1; int e = r / 32; r %= 32; kt = r / 2; jt = r % 2;
        src = W2 + (size_t)e*512*64; dst = uws + U_W2T + (size_t)e*64*512; K = 512; J = 64;
    } else {
        int r = bid - t2; kt = r / 16; jt = r % 16;
        src = Wenc; dst = uws + U_WENCT; K = 64; J = 512;
    }
    int ty = tid >> 5, tx = tid & 31;
    #pragma unroll
    for(int i = 0; i < 4; i++)
        sT[ty + i*8][tx] = src[(size_t)(kt*32 + ty + i*8)*J + jt*32 + tx];
    __syncthreads();
    #pragma unroll
    for(int i = 0; i < 4; i++)
        dst[(size_t)(jt*32 + ty + i*8)*K + kt*32 + tx] = f2bf(sT[tx][ty + i*8]);
}

// ---------------- k1: encoder + router + selection + XC, fully fused (1 block / sample) ----
#define PADX 72
__global__ __launch_bounds__(512) void k1_enc(const float* __restrict__ obs,
        const u16* __restrict__ uws, const float* __restrict__ Wr,
        const float* __restrict__ br, const int* __restrict__ phase,
        const int* __restrict__ t_arr, float* __restrict__ ws){
    __shared__ u16  sX[256 * PADX];    // 36.9 KB
    __shared__ float sBias[512];
    __shared__ float sG[512];
    __shared__ float sRed[8][6];
    int b = blockIdx.x, tid = threadIdx.x;
    {   // stage obs 256x64 -> bf16
        int row = tid >> 1, c0 = (tid & 1) * 32;
        const f32x4* src = (const f32x4*)&obs[((size_t)b*256 + row)*64 + c0];
        u16* dst = &sX[row*PADX + c0];
        #pragma unroll
        for(int i = 0; i < 8; i++){
            f32x4 v = src[i];
            u16x4 pk; pk.x = f2bf(v.x); pk.y = f2bf(v.y); pk.z = f2bf(v.z); pk.w = f2bf(v.w);
            *(u16x4*)(dst + i*4) = pk;
        }
    }
    sBias[tid] = ws[WS_BIAS + b*512 + tid];
    __syncthreads();
    int w = tid >> 6, l = tid & 63, lr = l & 15, lk = (l >> 4) * 8;
    const u16* wencT = uws + U_WENCT;
    s16x8 bf[4][2];
    float bias[4];
    #pragma unroll
    for(int n = 0; n < 4; n++){
        int col = w*64 + n*16 + lr;
        bf[n][0] = *(const s16x8*)&wencT[col*64 + lk];
        bf[n][1] = *(const s16x8*)&wencT[col*64 + 32 + lk];
        bias[n]  = sBias[col];
    }
    float cac[4] = {0.f, 0.f, 0.f, 0.f};
    for(int mt = 0; mt < 16; mt++){
        s16x8 a0 = *(const s16x8*)&sX[(mt*16 + lr)*PADX + lk];
        s16x8 a1 = *(const s16x8*)&sX[(mt*16 + lr)*PADX + 32 + lk];
        #pragma unroll
        for(int n = 0; n < 4; n++){
            f32x4 acc = {bias[n], bias[n], bias[n], bias[n]};
            mfma16(acc, a0, bf[n][0]);
            mfma16(acc, a1, bf[n][1]);
            cac[n] += gelu_f(acc.x) + gelu_f(acc.y) + gelu_f(acc.z) + gelu_f(acc.w);
        }
    }
    #pragma unroll
    for(int n = 0; n < 4; n++){
        cac[n] += __shfl_xor(cac[n], 16);
        cac[n] += __shfl_xor(cac[n], 32);
    }
    if(l < 16){
        #pragma unroll
        for(int n = 0; n < 4; n++)
            sG[w*64 + n*16 + l] = cac[n] * (1.0f/256.0f);
    }
    __syncthreads();
    float gv = sG[tid];
    u16* XC = (u16*)(ws + WS_XC);
    XC[b*1024 + tid] = f2bf(gv);
    int tv = t_arr[b];
    {
        float fr = ws[WS_FREQS + (tid & 255)];
        float ang = (float)tv * fr;
        XC[b*1024 + 512 + tid] = f2bf((tid < 256) ? sinf(ang) : cosf(ang));
    }
    float p6[6];
    #pragma unroll
    for(int e = 0; e < 6; e++) p6[e] = gv * Wr[tid*6 + e];
    #pragma unroll
    for(int off = 32; off > 0; off >>= 1)
        #pragma unroll
        for(int e = 0; e < 6; e++) p6[e] += __shfl_down(p6[e], off);
    if(l == 0)
        #pragma unroll
        for(int e = 0; e < 6; e++) sRed[w][e] = p6[e];
    __syncthreads();
    if(tid == 0){
        float logit[6], mx = -1e30f;
        #pragma unroll
        for(int e = 0; e < 6; e++){
            float s = 0.f;
            #pragma unroll
            for(int q = 0; q < 8; q++) s += sRed[q][e];
            logit[e] = s + br[e];
            mx = fmaxf(mx, logit[e]);
        }
        float s = 0.f, p[6];
        #pragma unroll
        for(int e = 0; e < 6; e++){ p[e] = expf(logit[e] - mx); s += p[e]; }
        float inv = 1.0f / s;
        #pragma unroll
        for(int e = 0; e < 6; e++) ws[WS_PROBS + b*6 + e] = p[e] * inv;
        int ph = phase[b];
        int sel = ph + ((logit[ph + 3] > logit[ph]) ? 3 : 0);
        ((int*)ws)[WS_SELECTED + b] = sel;
    }
}

// ---------------- k3: hstat GEMM with INLINE row-list build (no k2b) ----------------
__global__ __launch_bounds__(256) void k3_hstat(const u16* __restrict__ uws,
        const float* __restrict__ b1, float* __restrict__ ws){
    __shared__ int sSrc[64], sDst[64];
    __shared__ int sCnt[8][6], sBase[8][6], sSec[6], sTot[6];
    __shared__ int sChunk[16][3];
    __shared__ int sNch;
    int bid = blockIdx.x, tid = threadIdx.x;
    int w = tid >> 6, l = tid & 63;
    int* wsi = (int*)ws;
    if(bid == 0 && tid == 0) wsi[WS_FLAG] = 0;   // reset k5 join counter
    // --- row-list build (redundant per block, parallel) ---
    int sv0 = wsi[WS_SELECTED + tid];
    int sv1 = wsi[WS_SELECTED + 256 + tid];
    unsigned long long mym0 = 0, mym1 = 0;
    #pragma unroll
    for(int e = 0; e < 6; e++){
        unsigned long long m0 = __ballot(sv0 == e);
        unsigned long long m1 = __ballot(sv1 == e);
        if(l == 0){ sCnt[w][e] = __popcll(m0); sCnt[4 + w][e] = __popcll(m1); }
        if(sv0 == e) mym0 = m0;
        if(sv1 == e) mym1 = m1;
    }
    if(tid < 64){ sSrc[tid] = 0; sDst[tid] = -1; }
    __syncthreads();
    if(tid == 0){
        int o = 0;
        for(int e = 0; e < 6; e++){
            sSec[e] = o; int t0 = 0;
            for(int g = 0; g < 8; g++){ sBase[g][e] = o; o += sCnt[g][e]; t0 += sCnt[g][e]; }
            sTot[e] = t0; o += 4;
        }
        int nch = 0;
        for(int e = 0; e < 6; e++){
            int len = sTot[e] + 4, st = sSec[e];
            for(int s = 0; s < len; s += 64){
                sChunk[nch][0] = e; sChunk[nch][1] = st + s;
                sChunk[nch][2] = (len - s < 64) ? (len - s) : 64; nch++;
            }
        }
        sNch = nch;
    }
    __syncthreads();
    int c = bid >> 3, jt = bid & 7;
    if(c >= sNch) return;
    int e     = sChunk[c][0];
    int start = sChunk[c][1];
    int len   = sChunk[c][2];
    {
        int rank = __popcll(mym0 & ((1ull << l) - 1ull));
        int pos = sBase[w][sv0] + rank - start;
        if(pos >= 0 && pos < len){ sSrc[pos] = tid; sDst[pos] = WS_HSTAT + tid*512; }
    }
    {
        int rank = __popcll(mym1 & ((1ull << l) - 1ull));
        int pos = sBase[4 + w][sv1] + rank - start;
        if(pos >= 0 && pos < len){ sSrc[pos] = 256 + tid; sDst[pos] = WS_HSTAT + (256 + tid)*512; }
    }
    if(tid < 24){
        int ea = tid >> 2, ba = tid & 3;
        int pos = sSec[ea] + sTot[ea] + ba - start;
        if(pos >= 0 && pos < len){ sSrc[pos] = ba; sDst[pos] = WS_HSTAT2 + (ea*4 + ba)*512; }
    }
    __syncthreads();
    // --- GEMM ---
    int lr = l & 15, lk = (l >> 4) * 8;
    int col = jt*64 + w*16 + lr;
    const u16* XC = (const u16*)(ws + WS_XC);
    const u16* rowA[4];
    #pragma unroll
    for(int mt = 0; mt < 4; mt++)
        rowA[mt] = XC + (size_t)sSrc[mt*16 + lr]*1024 + lk;
    const u16* bp = uws + U_W1T + ((size_t)e*512 + col)*1088 + 64 + lk;
    f32x4 acc[4];
    {
        float bv = b1[e*512 + col];
        f32x4 z = {bv, bv, bv, bv};
        #pragma unroll
        for(int mt = 0; mt < 4; mt++) acc[mt] = z;
    }
    #pragma unroll 4
    for(int ks = 0; ks < 32; ks++){
        s16x8 bb = *(const s16x8*)(bp + ks*32);
        s16x8 a0 = *(const s16x8*)(rowA[0] + ks*32);
        s16x8 a1 = *(const s16x8*)(rowA[1] + ks*32);
        s16x8 a2 = *(const s16x8*)(rowA[2] + ks*32);
        s16x8 a3 = *(const s16x8*)(rowA[3] + ks*32);
        mfma16(acc[0], a0, bb);
        mfma16(acc[1], a1, bb);
        mfma16(acc[2], a2, bb);
        mfma16(acc[3], a3, bb);
    }
    #pragma unroll
    for(int mt = 0; mt < 4; mt++){
        #pragma unroll
        for(int rg = 0; rg < 4; rg++){
            int r = mt*16 + (l >> 4)*4 + rg;
            int d = sDst[r];
            if(d >= 0) ws[d + col] = acc[mt][rg];
        }
    }
}

// ---------------- k4: per-sample FFN via MFMA (store blocks first) ----------------
#define PADN 72
#define PADH 520
__global__ __launch_bounds__(512) void k4_ffn(const float* __restrict__ fut,
        const float* __restrict__ eps, const int* __restrict__ t_arr,
        const u16* __restrict__ uws, const float* __restrict__ b2,
        float* __restrict__ ws){
    __shared__ u16 sN[64 * PADN];
    __shared__ u16 sH[64 * PADH];    // [tf][j] layout
    __shared__ float sHs[512];
    __shared__ float sRed[8];
    int tid = threadIdx.x, bid = blockIdx.x;
    int* wsi = (int*)ws;
    int b, e, store;
    if(bid < 24){ e = bid >> 2; b = bid & 3; store = 1; }
    else { b = bid - 24; e = wsi[WS_SELECTED + b]; store = 0; }
    sHs[tid] = store ? ws[WS_HSTAT2 + (e*4 + b)*512 + tid] : ws[WS_HSTAT + b*512 + tid];
    int tv = t_arr[b];
    float ab = ws[WS_ALPHAS + tv];
    float sa = sqrtf(ab), sb = sqrtf(1.0f - ab);
    {
        int r = tid >> 3, c0 = (tid & 7) * 8;
        const f32x4* pf = (const f32x4*)&fut[((size_t)b*64 + r)*64 + c0];
        const f32x4* pe = (const f32x4*)&eps[((size_t)b*64 + r)*64 + c0];
        f32x4 f0 = pf[0], f1 = pf[1], e0 = pe[0], e1 = pe[1];
        u16x4 p0, p1;
        p0.x = f2bf(sa*f0.x + sb*e0.x); p0.y = f2bf(sa*f0.y + sb*e0.y);
        p0.z = f2bf(sa*f0.z + sb*e0.z); p0.w = f2bf(sa*f0.w + sb*e0.w);
        p1.x = f2bf(sa*f1.x + sb*e1.x); p1.y = f2bf(sa*f1.y + sb*e1.y);
        p1.z = f2bf(sa*f1.z + sb*e1.z); p1.w = f2bf(sa*f1.w + sb*e1.w);
        *(u16x4*)&sN[r*PADN + c0]     = p0;
        *(u16x4*)&sN[r*PADN + c0 + 4] = p1;
    }
    __syncthreads();
    int w = tid >> 6, l = tid & 63, lr = l & 15, lk = (l >> 4) * 8;
    const u16* w1T = uws + U_W1T;
    const u16* w2T = uws + U_W2T;
    s16x8 aw[4][2];
    #pragma unroll
    for(int mt = 0; mt < 4; mt++){
        int jrow = w*64 + mt*16 + lr;
        aw[mt][0] = *(const s16x8*)&w1T[((size_t)e*512 + jrow)*1088 + lk];
        aw[mt][1] = *(const s16x8*)&w1T[((size_t)e*512 + jrow)*1088 + 32 + lk];
    }
    #pragma unroll
    for(int nt = 0; nt < 4; nt++){
        s16x8 nb0 = *(const s16x8*)&sN[(nt*16 + lr)*PADN + lk];
        s16x8 nb1 = *(const s16x8*)&sN[(nt*16 + lr)*PADN + 32 + lk];
        #pragma unroll
        for(int mt = 0; mt < 4; mt++){
            int j0 = w*64 + mt*16 + (l >> 4)*4;
            f32x4 acc = *(const f32x4*)&sHs[j0];
            mfma16(acc, aw[mt][0], nb0);
            mfma16(acc, aw[mt][1], nb1);
            u16x4 pk;
            pk.x = f2bf(gelu_f(acc.x)); pk.y = f2bf(gelu_f(acc.y));
            pk.z = f2bf(gelu_f(acc.z)); pk.w = f2bf(gelu_f(acc.w));
            *(u16x4*)&sH[(nt*16 + lr)*PADH + j0] = pk;   // single b64 write
        }
    }
    __syncthreads();
    int mtg = (w >> 2) << 1;
    int nt  = w & 3;
    f32x4 oacc[2];
    {
        float bz = b2[e*64 + nt*16 + lr];
        f32x4 z = {bz, bz, bz, bz}; oacc[0] = z; oacc[1] = z;
    }
    for(int ks = 0; ks < 16; ks++){
        s16x8 bb = *(const s16x8*)&w2T[((size_t)e*64 + nt*16 + lr)*512 + ks*32 + lk];
        #pragma unroll
        for(int i = 0; i < 2; i++){
            s16x8 a = *(const s16x8*)&sH[((mtg + i)*16 + lr)*PADH + ks*32 + lk];
            mfma16(oacc[i], a, bb);
        }
    }
    if(store){
        #pragma unroll
        for(int i = 0; i < 2; i++)
            #pragma unroll
            for(int rg = 0; rg < 4; rg++){
                int row = (mtg + i)*16 + (l >> 4)*4 + rg;
                int col = nt*16 + lr;
                ws[WS_OUTSUB + (e*4 + b)*4096 + row*64 + col] = oacc[i][rg];
            }
    } else {
        float ls = 0.f;
        #pragma unroll
        for(int i = 0; i < 2; i++)
            #pragma unroll
            for(int rg = 0; rg < 4; rg++){
                int row = (mtg + i)*16 + (l >> 4)*4 + rg;
                int col = nt*16 + lr;
                float d = oacc[i][rg] - eps[((size_t)b*64 + row)*64 + col];
                ls += d*d;
            }
        #pragma unroll
        for(int off = 32; off > 0; off >>= 1) ls += __shfl_down(ls, off);
        if(l == 0) sRed[w] = ls;
        __syncthreads();
        if(tid == 0){
            float s = 0.f;
            #pragma unroll
            for(int q = 0; q < 8; q++) s += sRed[q];
            const float pw[3] = {1.f, 5.f, 5.f};
            ws[WS_LOSSB + b] = (s * (1.0f/4096.0f)) * pw[e % 3];
        }
    }
}

// ---------------- k5: chain/smooth partials + atomic-join finalize (one launch) ----------
__global__ __launch_bounds__(256) void k5_final(float* __restrict__ ws, float* __restrict__ out){
    int bid = blockIdx.x, tid = threadIdx.x;
    int* wsi = (int*)ws;
    if(bid < 13){
        __shared__ float red[256];
        float s = 0.f;
        if(bid < 7){
            const int pa[7] = {0,1,3,4,0,1,2};
            const int pb[7] = {1,2,4,5,3,4,5};
            const float* A  = &ws[WS_OUTSUB + pa[bid]*16384];
            const float* Bp = &ws[WS_OUTSUB + pb[bid]*16384];
            for(int i = tid; i < 4096; i += 256){
                f32x4 a = *(const f32x4*)&A[i*4];
                f32x4 c = *(const f32x4*)&Bp[i*4];
                f32x4 d = a - c;
                s += d.x*d.x + d.y*d.y + d.z*d.z + d.w*d.w;
            }
            s *= (1.0f/16384.0f);
        } else {
            int e = bid - 7;
            const float* O = &ws[WS_OUTSUB + e*16384];
            for(int i = tid; i < 4*63*16; i += 256){
                int sm = i / (63*16); int r = i % (63*16);
                int tf = r / 16; int f4 = (r % 16) * 4;
                f32x4 a = *(const f32x4*)&O[(sm*64 + tf + 1)*64 + f4];
                f32x4 c = *(const f32x4*)&O[(sm*64 + tf)*64 + f4];
                f32x4 d = a - c;
                s += d.x*d.x + d.y*d.y + d.z*d.z + d.w*d.w;
            }
            s *= (1.0f/16128.0f) * 0.5f;
        }
        red[tid] = s;
        __syncthreads();
        for(int st = 128; st > 0; st >>= 1){
            if(tid < st) red[tid] += red[tid + st];
            __syncthreads();
        }
        if(tid == 0){
            ws[WS_PARTS + bid] = red[0];
            __threadfence();
            atomicAdd(&wsi[WS_FLAG], 1);
        }
        return;
    }
    // bid == 13: join, then finalize
    if(tid == 0){
        while(atomicAdd(&wsi[WS_FLAG], 0) < 13) __builtin_amdgcn_s_sleep(2);
    }
    __syncthreads();
    __threadfence();
    __shared__ float sW[4];
    __shared__ float sF[4][6], sP[4][6];
    int w = tid >> 6, l = tid & 63;
    int sel0 = wsi[WS_SELECTED + tid];
    int sel1 = wsi[WS_SELECTED + 256 + tid];
    float lv = ws[WS_LOSSB + tid] + ws[WS_LOSSB + 256 + tid];
    float pv[6], cf[6];
    #pragma unroll
    for(int e = 0; e < 6; e++){
        pv[e] = ws[WS_PROBS + tid*6 + e] + ws[WS_PROBS + (256 + tid)*6 + e];
        cf[e] = ((sel0 == e) ? 1.f : 0.f) + ((sel1 == e) ? 1.f : 0.f);
    }
    #pragma unroll
    for(int off = 32; off > 0; off >>= 1){
        lv += __shfl_down(lv, off);
        #pragma unroll
        for(int e = 0; e < 6; e++){
            pv[e] += __shfl_down(pv[e], off);
            cf[e] += __shfl_down(cf[e], off);
        }
    }
    if(l == 0){
        sW[w] = lv;
        #pragma unroll
        for(int e = 0; e < 6; e++){ sF[w][e] = cf[e]; sP[w][e] = pv[e]; }
    }
    __syncthreads();
    if(tid == 0){
        float total = 0.f;
        for(int q = 0; q < 4; q++) total += sW[q];
        total *= (1.0f/512.0f);
        volatile float* vp = ws + WS_PARTS;
        float reg = 0.f;
        for(int p = 0; p < 13; p++) reg += vp[p];
        total += 0.01f * reg;
        float lb = 0.f;
        for(int e = 0; e < 6; e++){
            float f = 0.f, pp = 0.f;
            for(int q = 0; q < 4; q++){ f += sF[q][e]; pp += sP[q][e]; }
            lb += (f * (1.0f/512.f)) * (pp * (1.0f/512.f));
        }
        out[0] = total + 0.01f * 6.0f * lb;
    }
}

extern "C" void kernel_launch(void* const* d_in, const int* in_sizes, int n_in,
                              void* d_out, int out_size, void* d_ws, size_t ws_size,
                              hipStream_t stream){
    const float* obs  = (const float*)d_in[0];
    const float* fut  = (const float*)d_in[1];
    const float* stat = (const float*)d_in[2];
    const float* eps  = (const float*)d_in[3];
    const int*   phase= (const int*)d_in[4];
    const int*   t    = (const int*)d_in[5];
    const float* Wenc = (const float*)d_in[6];
    const float* benc = (const float*)d_in[7];
    const float* Wstat= (const float*)d_in[8];
    const float* Wr   = (const float*)d_in[9];
    const float* br   = (const float*)d_in[10];
    const float* W1   = (const float*)d_in[11];
    const float* b1   = (const float*)d_in[12];
    const float* W2   = (const float*)d_in[13];
    const float* b2   = (const float*)d_in[14];
    float* ws  = (float*)d_ws;
    u16*   uws = (u16*)((char*)d_ws + WS_U16BYTE);
    float* out = (float*)d_out;

    k0T<<<3553, 256, 0, stream>>>(Wenc, W1, W2, stat, Wstat, benc, uws, ws);
    k1_enc<<<512, 512, 0, stream>>>(obs, uws, Wr, br, phase, t, ws);
    k3_hstat<<<112, 256, 0, stream>>>(uws, b1, ws);
    k4_ffn<<<536, 512, 0, stream>>>(fut, eps, t, uws, b2, ws);
    k5_final<<<14, 256, 0, stream>>>(ws, out);
}

// Round 8
// 104.021 us; speedup vs baseline: 7.6818x; 1.0010x over previous
//
#include <hip/hip_runtime.h>

typedef float  f32x4 __attribute__((ext_vector_type(4)));
typedef short  s16x8 __attribute__((ext_vector_type(8)));
typedef unsigned short u16;
typedef u16    u16x4 __attribute__((ext_vector_type(4)));

#define TIMESTEPS 1000

// ---- ws float-offset map ----
#define WS_ALPHAS   0        // 1000 f
#define WS_FREQS    1024     // 256 f
#define WS_PROBS    1536     // 512*6 f
#define WS_SELECTED 4608     // 512 int
#define WS_LOSSB    5632     // 512 f
#define WS_PARTS    7680     // 13 f
#define WS_FLAG     7700     // 1 int (k5 join counter; reset by k3 block 0)
#define WS_XC       270336   // 512*1024 bf16 (u16) = 512 KB
#define WS_HSTAT    532480   // 512*512 f
#define WS_HSTAT2   794624   // 6*4*512 f
#define WS_OUTSUB   806912   // 6*4*64*64 f
#define WS_U16BYTE  3620864  // byte offset of u16 weight region (16B aligned)
#define WS_BIAS     2691072  // 512*512 f
// u16-offsets inside u16 region
#define U_WENCT     0        // 512*64
#define U_W1T       32768    // 6*512*1088
#define U_W2T       3375104  // 6*64*512

__device__ __forceinline__ u16 f2bf(float x){
    unsigned u = __builtin_bit_cast(unsigned, x);
    unsigned r = (u + 0x7FFFu + ((u >> 16) & 1u)) >> 16;
    return (u16)r;
}

__device__ __forceinline__ float gelu_f(float x){
    float x2 = x * x;
    float t  = x * fmaf(0.035677408136f, x2, 0.7978845608028654f);
    float ex = __builtin_amdgcn_exp2f(t * 2.885390081777927f);
    float r  = __builtin_amdgcn_rcpf(ex + 1.0f);
    return fmaf(-x, r, x);
}

__device__ __forceinline__ void mfma16(f32x4& c, s16x8 a, s16x8 b){
    asm volatile("v_mfma_f32_16x16x32_bf16 %0, %1, %2, %0" : "+v"(c) : "v"(a), "v"(b));
}

// ---------------- k0T: weight transposes + alphas/freqs + bias table ----------------
__global__ __launch_bounds__(256) void k0T(const float* __restrict__ Wenc,
                                           const float* __restrict__ W1,
                                           const float* __restrict__ W2,
                                           const float* __restrict__ stat,
                                           const float* __restrict__ Wstat,
                                           const float* __restrict__ benc,
                                           u16* __restrict__ uws,
                                           float* __restrict__ ws){
    __shared__ float sT[32][33];
    int bid = blockIdx.x, tid = threadIdx.x;
    const int t1 = 6*34*16, t2 = t1 + 6*16*2, t3 = t2 + 2*16;
    if(bid == t3){
        __shared__ float sp[256];
        for(int k = tid; k < 256; k += 256)
            ws[WS_FREQS + k] = expf(-logf(10000.0f) * (float)k / 256.0f);
        float p = 1.f;
        #pragma unroll
        for(int r = 0; r < 4; r++){
            int i = tid*4 + r;
            if(i < TIMESTEPS){
                float beta = 0.0001f + (0.02f - 0.0001f) * ((float)i / 999.0f);
                p *= (1.0f - beta);
            }
        }
        sp[tid] = p;
        __syncthreads();
        for(int st = 1; st < 256; st <<= 1){
            float v = (tid >= st) ? sp[tid - st] : 1.0f;
            __syncthreads();
            sp[tid] *= v;
            __syncthreads();
        }
        float run = (tid == 0) ? 1.0f : sp[tid - 1];
        for(int r = 0; r < 4; r++){
            int i = tid*4 + r;
            if(i < TIMESTEPS){
                float beta = 0.0001f + (0.02f - 0.0001f) * ((float)i / 999.0f);
                run *= (1.0f - beta);
                ws[WS_ALPHAS + i] = run;
            }
        }
        return;
    }
    if(bid > t3){
        __shared__ float sSt[8*32];
        int g = bid - t3 - 1;              // 0..63
        int b0 = g*8;
        sSt[tid & 255] = stat[b0*32 + (tid & 255)];
        __syncthreads();
        #pragma unroll
        for(int half = 0; half < 2; half++){
            int j = tid + half*256;
            float acc[8] = {0,0,0,0,0,0,0,0};
            for(int s = 0; s < 32; s++){
                float wv = Wstat[s*512 + j];
                #pragma unroll
                for(int bb = 0; bb < 8; bb++) acc[bb] += sSt[bb*32 + s] * wv;
            }
            float bz = benc[j];
            #pragma unroll
            for(int bb = 0; bb < 8; bb++)
                ws[WS_BIAS + (b0 + bb)*512 + j] = acc[bb] + bz;
        }
        return;
    }
    const float* src; u16* dst; int K, J, kt, jt;
    if(bid < t1){
        int e = bid / 544, r = bid % 544; kt = r / 16; jt = r % 16;
        src = W1 + (size_t)e*1088*512; dst = uws + U_W1T + (size_t)e*512*1088; K = 1088; J = 512;
    } else if(bid < t2){
        int r = bid - t1; int e = r / 32; r %= 32; kt = r / 2; jt = r % 2;
        src = W2 + (size_t)e*512*64; dst = uws + U_W2T + (size_t)e*64*512; K = 512; J = 64;
    } else {
        int r = bid - t2; kt = r / 16; jt = r % 16;
        src = Wenc; dst = uws + U_WENCT; K = 64; J = 512;
    }
    int ty = tid >> 5, tx = tid & 31;
    #pragma unroll
    for(int i = 0; i < 4; i++)
        sT[ty + i*8][tx] = src[(size_t)(kt*32 + ty + i*8)*J + jt*32 + tx];
    __syncthreads();
    #pragma unroll
    for(int i = 0; i < 4; i++)
        dst[(size_t)(jt*32 + ty + i*8)*K + kt*32 + tx] = f2bf(sT[tx][ty + i*8]);
}

// ---------------- k1: encoder + router + selection + XC, fully fused (1 block / sample) ----
#define PADX 72
__global__ __launch_bounds__(512) void k1_enc(const float* __restrict__ obs,
        const u16* __restrict__ uws, const float* __restrict__ Wr,
        const float* __restrict__ br, const int* __restrict__ phase,
        const int* __restrict__ t_arr, float* __restrict__ ws){
    __shared__ u16  sX[256 * PADX];    // 36.9 KB
    __shared__ float sBias[512];
    __shared__ float sG[512];
    __shared__ float sRed[8][6];
    int b = blockIdx.x, tid = threadIdx.x;
    {   // stage obs 256x64 -> bf16
        int row = tid >> 1, c0 = (tid & 1) * 32;
        const f32x4* src = (const f32x4*)&obs[((size_t)b*256 + row)*64 + c0];
        u16* dst = &sX[row*PADX + c0];
        #pragma unroll
        for(int i = 0; i < 8; i++){
            f32x4 v = src[i];
            u16x4 pk; pk.x = f2bf(v.x); pk.y = f2bf(v.y); pk.z = f2bf(v.z); pk.w = f2bf(v.w);
            *(u16x4*)(dst + i*4) = pk;
        }
    }
    sBias[tid] = ws[WS_BIAS + b*512 + tid];
    __syncthreads();
    int w = tid >> 6, l = tid & 63, lr = l & 15, lk = (l >> 4) * 8;
    const u16* wencT = uws + U_WENCT;
    s16x8 bf[4][2];
    float bias[4];
    #pragma unroll
    for(int n = 0; n < 4; n++){
        int col = w*64 + n*16 + lr;
        bf[n][0] = *(const s16x8*)&wencT[col*64 + lk];
        bf[n][1] = *(const s16x8*)&wencT[col*64 + 32 + lk];
        bias[n]  = sBias[col];
    }
    float cac[4] = {0.f, 0.f, 0.f, 0.f};
    for(int mt = 0; mt < 16; mt++){
        s16x8 a0 = *(const s16x8*)&sX[(mt*16 + lr)*PADX + lk];
        s16x8 a1 = *(const s16x8*)&sX[(mt*16 + lr)*PADX + 32 + lk];
        #pragma unroll
        for(int n = 0; n < 4; n++){
            f32x4 acc = {bias[n], bias[n], bias[n], bias[n]};
            mfma16(acc, a0, bf[n][0]);
            mfma16(acc, a1, bf[n][1]);
            cac[n] += gelu_f(acc.x) + gelu_f(acc.y) + gelu_f(acc.z) + gelu_f(acc.w);
        }
    }
    #pragma unroll
    for(int n = 0; n < 4; n++){
        cac[n] += __shfl_xor(cac[n], 16);
        cac[n] += __shfl_xor(cac[n], 32);
    }
    if(l < 16){
        #pragma unroll
        for(int n = 0; n < 4; n++)
            sG[w*64 + n*16 + l] = cac[n] * (1.0f/256.0f);
    }
    __syncthreads();
    float gv = sG[tid];
    u16* XC = (u16*)(ws + WS_XC);
    XC[b*1024 + tid] = f2bf(gv);
    int tv = t_arr[b];
    {
        float fr = ws[WS_FREQS + (tid & 255)];
        float ang = (float)tv * fr;
        XC[b*1024 + 512 + tid] = f2bf((tid < 256) ? sinf(ang) : cosf(ang));
    }
    float p6[6];
    #pragma unroll
    for(int e = 0; e < 6; e++) p6[e] = gv * Wr[tid*6 + e];
    #pragma unroll
    for(int off = 32; off > 0; off >>= 1)
        #pragma unroll
        for(int e = 0; e < 6; e++) p6[e] += __shfl_down(p6[e], off);
    if(l == 0)
        #pragma unroll
        for(int e = 0; e < 6; e++) sRed[w][e] = p6[e];
    __syncthreads();
    if(tid == 0){
        float logit[6], mx = -1e30f;
        #pragma unroll
        for(int e = 0; e < 6; e++){
            float s = 0.f;
            #pragma unroll
            for(int q = 0; q < 8; q++) s += sRed[q][e];
            logit[e] = s + br[e];
            mx = fmaxf(mx, logit[e]);
        }
        float s = 0.f, p[6];
        #pragma unroll
        for(int e = 0; e < 6; e++){ p[e] = expf(logit[e] - mx); s += p[e]; }
        float inv = 1.0f / s;
        #pragma unroll
        for(int e = 0; e < 6; e++) ws[WS_PROBS + b*6 + e] = p[e] * inv;
        int ph = phase[b];
        int sel = ph + ((logit[ph + 3] > logit[ph]) ? 3 : 0);
        ((int*)ws)[WS_SELECTED + b] = sel;
    }
}

// ---------------- k3: hstat GEMM with INLINE row-list build (no k2b) ----------------
__global__ __launch_bounds__(256) void k3_hstat(const u16* __restrict__ uws,
        const float* __restrict__ b1, float* __restrict__ ws){
    __shared__ int sSrc[64], sDst[64];
    __shared__ int sCnt[8][6], sBase[8][6], sSec[6], sTot[6];
    __shared__ int sChunk[16][3];
    __shared__ int sNch;
    int bid = blockIdx.x, tid = threadIdx.x;
    int w = tid >> 6, l = tid & 63;
    int* wsi = (int*)ws;
    if(bid == 0 && tid == 0) wsi[WS_FLAG] = 0;   // reset k5 join counter
    // --- row-list build (redundant per block, parallel) ---
    int sv0 = wsi[WS_SELECTED + tid];
    int sv1 = wsi[WS_SELECTED + 256 + tid];
    unsigned long long mym0 = 0, mym1 = 0;
    #pragma unroll
    for(int e = 0; e < 6; e++){
        unsigned long long m0 = __ballot(sv0 == e);
        unsigned long long m1 = __ballot(sv1 == e);
        if(l == 0){ sCnt[w][e] = __popcll(m0); sCnt[4 + w][e] = __popcll(m1); }
        if(sv0 == e) mym0 = m0;
        if(sv1 == e) mym1 = m1;
    }
    if(tid < 64){ sSrc[tid] = 0; sDst[tid] = -1; }
    __syncthreads();
    if(tid == 0){
        int o = 0;
        for(int e = 0; e < 6; e++){
            sSec[e] = o; int t0 = 0;
            for(int g = 0; g < 8; g++){ sBase[g][e] = o; o += sCnt[g][e]; t0 += sCnt[g][e]; }
            sTot[e] = t0; o += 4;
        }
        int nch = 0;
        for(int e = 0; e < 6; e++){
            int len = sTot[e] + 4, st = sSec[e];
            for(int s = 0; s < len; s += 64){
                sChunk[nch][0] = e; sChunk[nch][1] = st + s;
                sChunk[nch][2] = (len - s < 64) ? (len - s) : 64; nch++;
            }
        }
        sNch = nch;
    }
    __syncthreads();
    int c = bid >> 3, jt = bid & 7;
    if(c >= sNch) return;
    int e     = sChunk[c][0];
    int start = sChunk[c][1];
    int len   = sChunk[c][2];
    {
        int rank = __popcll(mym0 & ((1ull << l) - 1ull));
        int pos = sBase[w][sv0] + rank - start;
        if(pos >= 0 && pos < len){ sSrc[pos] = tid; sDst[pos] = WS_HSTAT + tid*512; }
    }
    {
        int rank = __popcll(mym1 & ((1ull << l) - 1ull));
        int pos = sBase[4 + w][sv1] + rank - start;
        if(pos >= 0 && pos < len){ sSrc[pos] = 256 + tid; sDst[pos] = WS_HSTAT + (256 + tid)*512; }
    }
    if(tid < 24){
        int ea = tid >> 2, ba = tid & 3;
        int pos = sSec[ea] + sTot[ea] + ba - start;
        if(pos >= 0 && pos < len){ sSrc[pos] = ba; sDst[pos] = WS_HSTAT2 + (ea*4 + ba)*512; }
    }
    __syncthreads();
    // --- GEMM ---
    int lr = l & 15, lk = (l >> 4) * 8;
    int col = jt*64 + w*16 + lr;
    const u16* XC = (const u16*)(ws + WS_XC);
    const u16* rowA[4];
    #pragma unroll
    for(int mt = 0; mt < 4; mt++)
        rowA[mt] = XC + (size_t)sSrc[mt*16 + lr]*1024 + lk;
    const u16* bp = uws + U_W1T + ((size_t)e*512 + col)*1088 + 64 + lk;
    f32x4 acc[4];
    {
        float bv = b1[e*512 + col];
        f32x4 z = {bv, bv, bv, bv};
        #pragma unroll
        for(int mt = 0; mt < 4; mt++) acc[mt] = z;
    }
    #pragma unroll 4
    for(int ks = 0; ks < 32; ks++){
        s16x8 bb = *(const s16x8*)(bp + ks*32);
        s16x8 a0 = *(const s16x8*)(rowA[0] + ks*32);
        s16x8 a1 = *(const s16x8*)(rowA[1] + ks*32);
        s16x8 a2 = *(const s16x8*)(rowA[2] + ks*32);
        s16x8 a3 = *(const s16x8*)(rowA[3] + ks*32);
        mfma16(acc[0], a0, bb);
        mfma16(acc[1], a1, bb);
        mfma16(acc[2], a2, bb);
        mfma16(acc[3], a3, bb);
    }
    #pragma unroll
    for(int mt = 0; mt < 4; mt++){
        #pragma unroll
        for(int rg = 0; rg < 4; rg++){
            int r = mt*16 + (l >> 4)*4 + rg;
            int d = sDst[r];
            if(d >= 0) ws[d + col] = acc[mt][rg];
        }
    }
}

// ---------------- k4: per-sample FFN via MFMA (store blocks first) ----------------
#define PADN 72
#define PADH 520
__global__ __launch_bounds__(512) void k4_ffn(const float* __restrict__ fut,
        const float* __restrict__ eps, const int* __restrict__ t_arr,
        const u16* __restrict__ uws, const float* __restrict__ b2,
        float* __restrict__ ws){
    __shared__ u16 sN[64 * PADN];
    __shared__ u16 sH[64 * PADH];    // [tf][j] layout
    __shared__ float sHs[512];
    __shared__ float sRed[8];
    int tid = threadIdx.x, bid = blockIdx.x;
    int* wsi = (int*)ws;
    int b, e, store;
    if(bid < 24){ e = bid >> 2; b = bid & 3; store = 1; }
    else { b = bid - 24; e = wsi[WS_SELECTED + b]; store = 0; }
    sHs[tid] = store ? ws[WS_HSTAT2 + (e*4 + b)*512 + tid] : ws[WS_HSTAT + b*512 + tid];
    int tv = t_arr[b];
    float ab = ws[WS_ALPHAS + tv];
    float sa = sqrtf(ab), sb = sqrtf(1.0f - ab);
    {
        int r = tid >> 3, c0 = (tid & 7) * 8;
        const f32x4* pf = (const f32x4*)&fut[((size_t)b*64 + r)*64 + c0];
        const f32x4* pe = (const f32x4*)&eps[((size_t)b*64 + r)*64 + c0];
        f32x4 f0 = pf[0], f1 = pf[1], e0 = pe[0], e1 = pe[1];
        u16x4 p0, p1;
        p0.x = f2bf(sa*f0.x + sb*e0.x); p0.y = f2bf(sa*f0.y + sb*e0.y);
        p0.z = f2bf(sa*f0.z + sb*e0.z); p0.w = f2bf(sa*f0.w + sb*e0.w);
        p1.x = f2bf(sa*f1.x + sb*e1.x); p1.y = f2bf(sa*f1.y + sb*e1.y);
        p1.z = f2bf(sa*f1.z + sb*e1.z); p1.w = f2bf(sa*f1.w + sb*e1.w);
        *(u16x4*)&sN[r*PADN + c0]     = p0;
        *(u16x4*)&sN[r*PADN + c0 + 4] = p1;
    }
    __syncthreads();
    int w = tid >> 6, l = tid & 63, lr = l & 15, lk = (l >> 4) * 8;
    const u16* w1T = uws + U_W1T;
    const u16* w2T = uws + U_W2T;
    s16x8 aw[4][2];
    #pragma unroll
    for(int mt = 0; mt < 4; mt++){
        int jrow = w*64 + mt*16 + lr;
        aw[mt][0] = *(const s16x8*)&w1T[((size_t)e*512 + jrow)*1088 + lk];
        aw[mt][1] = *(const s16x8*)&w1T[((size_t)e*512 + jrow)*1088 + 32 + lk];
    }
    #pragma unroll
    for(int nt = 0; nt < 4; nt++){
        s16x8 nb0 = *(const s16x8*)&sN[(nt*16 + lr)*PADN + lk];
        s16x8 nb1 = *(const s16x8*)&sN[(nt*16 + lr)*PADN + 32 + lk];
        #pragma unroll
        for(int mt = 0; mt < 4; mt++){
            int j0 = w*64 + mt*16 + (l >> 4)*4;
            f32x4 acc = *(const f32x4*)&sHs[j0];
            mfma16(acc, aw[mt][0], nb0);
            mfma16(acc, aw[mt][1], nb1);
            u16x4 pk;
            pk.x = f2bf(gelu_f(acc.x)); pk.y = f2bf(gelu_f(acc.y));
            pk.z = f2bf(gelu_f(acc.z)); pk.w = f2bf(gelu_f(acc.w));
            *(u16x4*)&sH[(nt*16 + lr)*PADH + j0] = pk;   // single b64 write
        }
    }
    __syncthreads();
    int mtg = (w >> 2) << 1;
    int nt  = w & 3;
    f32x4 oacc[2];
    {
        float bz = b2[e*64 + nt*16 + lr];
        f32x4 z = {bz, bz, bz, bz}; oacc[0] = z; oacc[1] = z;
    }
    for(int ks = 0; ks < 16; ks++){
        s16x8 bb = *(const s16x8*)&w2T[((size_t)e*64 + nt*16 + lr)*512 + ks*32 + lk];
        #pragma unroll
        for(int i = 0; i < 2; i++){
            s16x8 a = *(const s16x8*)&sH[((mtg + i)*16 + lr)*PADH + ks*32 + lk];
            mfma16(oacc[i], a, bb);
        }
    }
    if(store){
        #pragma unroll
        for(int i = 0; i < 2; i++)
            #pragma unroll
            for(int rg = 0; rg < 4; rg++){
                int row = (mtg + i)*16 + (l >> 4)*4 + rg;
                int col = nt*16 + lr;
                ws[WS_OUTSUB + (e*4 + b)*4096 + row*64 + col] = oacc[i][rg];
            }
    } else {
        float ls = 0.f;
        #pragma unroll
        for(int i = 0; i < 2; i++)
            #pragma unroll
            for(int rg = 0; rg < 4; rg++){
                int row = (mtg + i)*16 + (l >> 4)*4 + rg;
                int col = nt*16 + lr;
                float d = oacc[i][rg] - eps[((size_t)b*64 + row)*64 + col];
                ls += d*d;
            }
        #pragma unroll
        for(int off = 32; off > 0; off >>= 1) ls += __shfl_down(ls, off);
        if(l == 0) sRed[w] = ls;
        __syncthreads();
        if(tid == 0){
            float s = 0.f;
            #pragma unroll
            for(int q = 0; q < 8; q++) s += sRed[q];
            const float pw[3] = {1.f, 5.f, 5.f};
            ws[WS_LOSSB + b] = (s * (1.0f/4096.0f)) * pw[e % 3];
        }
    }
}

// ---------------- k5: chain/smooth partials + atomic-join finalize (one launch) ----------
__global__ __launch_bounds__(256) void k5_final(float* __restrict__ ws, float* __restrict__ out){
    int bid = blockIdx.x, tid = threadIdx.x;
    int* wsi = (int*)ws;
    if(bid < 13){
        __shared__ float red[256];
        float s = 0.f;
        if(bid < 7){
            const int pa[7] = {0,1,3,4,0,1,2};
            const int pb[7] = {1,2,4,5,3,4,5};
            const float* A  = &ws[WS_OUTSUB + pa[bid]*16384];
            const float* Bp = &ws[WS_OUTSUB + pb[bid]*16384];
            for(int i = tid; i < 4096; i += 256){
                f32x4 a = *(const f32x4*)&A[i*4];
                f32x4 c = *(const f32x4*)&Bp[i*4];
                f32x4 d = a - c;
                s += d.x*d.x + d.y*d.y + d.z*d.z + d.w*d.w;
            }
            s *= (1.0f/16384.0f);
        } else {
            int e = bid - 7;
            const float* O = &ws[WS_OUTSUB + e*16384];
            for(int i = tid; i < 4*63*16; i += 256){
                int sm = i / (63*16); int r = i % (63*16);
                int tf = r / 16; int f4 = (r % 16) * 4;
                f32x4 a = *(const f32x4*)&O[(sm*64 + tf + 1)*64 + f4];
                f32x4 c = *(const f32x4*)&O[(sm*64 + tf)*64 + f4];
                f32x4 d = a - c;
                s += d.x*d.x + d.y*d.y + d.z*d.z + d.w*d.w;
            }
            s *= (1.0f/16128.0f) * 0.5f;
        }
        red[tid] = s;
        __syncthreads();
        for(int st = 128; st > 0; st >>= 1){
            if(tid < st) red[tid] += red[tid + st];
            __syncthreads();
        }
        if(tid == 0){
            ws[WS_PARTS + bid] = red[0];
            __threadfence();
            atomicAdd(&wsi[WS_FLAG], 1);
        }
        return;
    }
    // bid == 13: join, then finalize
    if(tid == 0){
        while(atomicAdd(&wsi[WS_FLAG], 0) < 13) __builtin_amdgcn_s_sleep(2);
    }
    __syncthreads();
    __threadfence();
    __shared__ float sW[4];
    __shared__ float sF[4][6], sP[4][6];
    int w = tid >> 6, l = tid & 63;
    int sel0 = wsi[WS_SELECTED + tid];
    int sel1 = wsi[WS_SELECTED + 256 + tid];
    float lv = ws[WS_LOSSB + tid] + ws[WS_LOSSB + 256 + tid];
    float pv[6], cf[6];
    #pragma unroll
    for(int e = 0; e < 6; e++){
        pv[e] = ws[WS_PROBS + tid*6 + e] + ws[WS_PROBS + (256 + tid)*6 + e];
        cf[e] = ((sel0 == e) ? 1.f : 0.f) + ((sel1 == e) ? 1.f : 0.f);
    }
    #pragma unroll
    for(int off = 32; off > 0; off >>= 1){
        lv += __shfl_down(lv, off);
        #pragma unroll
        for(int e = 0; e < 6; e++){
            pv[e] += __shfl_down(pv[e], off);
            cf[e] += __shfl_down(cf[e], off);
        }
    }
    if(l == 0){
        sW[w] = lv;
        #pragma unroll
        for(int e = 0; e < 6; e++){ sF[w][e] = cf[e]; sP[w][e] = pv[e]; }
    }
    __syncthreads();
    if(tid == 0){
        float total = 0.f;
        for(int q = 0; q < 4; q++) total += sW[q];
        total *= (1.0f/512.0f);
        volatile float* vp = ws + WS_PARTS;
        float reg = 0.f;
        for(int p = 0; p < 13; p++) reg += vp[p];
        total += 0.01f * reg;
        float lb = 0.f;
        for(int e = 0; e < 6; e++){
            float f = 0.f, pp = 0.f;
            for(int q = 0; q < 4; q++){ f += sF[q][e]; pp += sP[q][e]; }
            lb += (f * (1.0f/512.f)) * (pp * (1.0f/512.f));
        }
        out[0] = total + 0.01f * 6.0f * lb;
    }
}

extern "C" void kernel_launch(void* const* d_in, const int* in_sizes, int n_in,
                              void* d_out, int out_size, void* d_ws, size_t ws_size,
                              hipStream_t stream){
    const float* obs  = (const float*)d_in[0];
    const float* fut  = (const float*)d_in[1];
    const float* stat = (const float*)d_in[2];
    const float* eps  = (const float*)d_in[3];
    const int*   phase= (const int*)d_in[4];
    const int*   t    = (const int*)d_in[5];
    const float* Wenc = (const float*)d_in[6];
    const float* benc = (const float*)d_in[7];
    const float* Wstat= (const float*)d_in[8];
    const float* Wr   = (const float*)d_in[9];
    const float* br   = (const float*)d_in[10];
    const float* W1   = (const float*)d_in[11];
    const float* b1   = (const float*)d_in[12];
    const float* W2   = (const float*)d_in[13];
    const float* b2   = (const float*)d_in[14];
    float* ws  = (float*)d_ws;
    u16*   uws = (u16*)((char*)d_ws + WS_U16BYTE);
    float* out = (float*)d_out;

    k0T<<<3553, 256, 0, stream>>>(Wenc, W1, W2, stat, Wstat, benc, uws, ws);
    k1_enc<<<512, 512, 0, stream>>>(obs, uws, Wr, br, phase, t, ws);
    k3_hstat<<<112, 256, 0, stream>>>(uws, b1, ws);
    k4_ffn<<<536, 512, 0, stream>>>(fut, eps, t, uws, b2, ws);
    k5_final<<<14, 256, 0, stream>>>(ws, out);
}